// Round 6
// baseline (277.858 us; speedup 1.0000x reference)
//
#include <hip/hip_runtime.h>
#include <hip/hip_bf16.h>
#include <stdint.h>

#define B_SZ 4
#define SEQ 2048
#define DM 1024
#define NH 16
#define DK 64
#define BH (B_SZ * NH)      // 64
#define M_TOT (B_SZ * SEQ)  // 8192

typedef unsigned short u16;
typedef u16 u16x8 __attribute__((ext_vector_type(8)));
typedef __bf16 bf16x8 __attribute__((ext_vector_type(8)));
typedef float f32x4 __attribute__((ext_vector_type(4)));

// native RNE fp32->bf16 (single v_cvt instr on gfx950)
__device__ __forceinline__ u16 f2bf(float f) {
    return __builtin_bit_cast(u16, (__bf16)f);
}

// truncating fp32->bf16 (1 shift; used only for P in [0,1] -- v7-verified)
__device__ __forceinline__ u16 f2bf_trunc(float f) {
    union { float f; uint32_t u; } v; v.f = f;
    return (u16)(v.u >> 16);
}

__device__ __forceinline__ f32x4 mfma16(u16x8 a, u16x8 b, f32x4 c) {
    return __builtin_amdgcn_mfma_f32_16x16x32_bf16(
        __builtin_bit_cast(bf16x8, a), __builtin_bit_cast(bf16x8, b), c, 0, 0, 0);
}

// async global->LDS, 16 B per lane; lds dest = wave-uniform base + lane*16
__device__ __forceinline__ void gload16_lds(const void* g, void* l) {
    __builtin_amdgcn_global_load_lds(
        (const __attribute__((address_space(1))) void*)(uintptr_t)g,
        (__attribute__((address_space(3))) void*)(uintptr_t)l, 16, 0, 0);
}

// ---------------- x fp32 -> bf16 ----------------
__global__ void cvt_bf16_kernel(const float* __restrict__ in, u16* __restrict__ out, int n4) {
    int i = blockIdx.x * blockDim.x + threadIdx.x;
    if (i < n4) {
        float4 v = ((const float4*)in)[i];
        ushort4 o;
        o.x = f2bf(v.x); o.y = f2bf(v.y); o.z = f2bf(v.z); o.w = f2bf(v.w);
        ((ushort4*)out)[i] = o;
    }
}

// ---------------- W [K][N] fp32 -> Wt [N][K] bf16 (z = weight index) ----------------
__global__ void transpose_w_kernel(const float* __restrict__ W0, const float* __restrict__ W1,
                                   u16* __restrict__ Wt) {
    __shared__ u16 tile[32][33];
    int bx = blockIdx.x, by = blockIdx.y, z = blockIdx.z;
    const float* W = z ? W1 : W0;
    u16* Wd = Wt + (size_t)z * DM * DM;
    int t = threadIdx.x;
    for (int i = 0; i < 4; i++) {
        int idx = t + i * 256;
        int r = idx >> 5, c = idx & 31;
        tile[r][c] = f2bf(W[(by * 32 + r) * DM + bx * 32 + c]);
    }
    __syncthreads();
    for (int i = 0; i < 4; i++) {
        int idx = t + i * 256;
        int r2 = idx >> 5, c2 = idx & 31;
        Wd[(bx * 32 + r2) * DM + by * 32 + c2] = tile[c2][r2];
    }
}

// ---------------- staging: one 128x64 K-tile (A and B) into LDS buf ----------------
// bf16 tiles: [128][64] u16, 128 B rows = 8 x 16B granules, granule ^= row&7 swizzle
// (global source pre-swizzled; same involution applied on read -> conflict-free).
// fp32 A tile: [128][64] f32, 256 B rows = 16 granules, granule ^= row&15.
template <int AFP32>
__device__ __forceinline__ void stage_tile(const void* Ag, const u16* Btg,
                                           char* Apart, char* Bpart, int buf, int kst,
                                           int m0, int n0, int wave, int lane) {
    const int K = DM;
    {   // B: bf16, 4 calls x 8 rows x 128 B
        int rw = lane >> 3, slot = lane & 7;
        int gsw = slot ^ rw;
        u16* Bb = (u16*)(Bpart + buf * (128 * 64 * 2));
        #pragma unroll
        for (int c = 0; c < 4; c++) {
            int r0 = wave * 32 + c * 8;
            gload16_lds(Btg + (size_t)(n0 + r0 + rw) * K + kst + gsw * 8, Bb + r0 * 64);
        }
    }
    if constexpr (AFP32) {   // A: fp32, 8 calls x 4 rows x 256 B
        int rw = lane >> 4, slot = lane & 15;
        float* Ab = (float*)(Apart + buf * (128 * 64 * 4));
        const float* Af = (const float*)Ag;
        #pragma unroll
        for (int c = 0; c < 8; c++) {
            int r0 = wave * 32 + c * 4;
            int gsw = slot ^ ((c * 4 + rw) & 15);
            gload16_lds(Af + (size_t)(m0 + r0 + rw) * K + kst + gsw * 4, Ab + r0 * 64);
        }
    } else {                 // A: bf16, 4 calls x 8 rows x 128 B
        int rw = lane >> 3, slot = lane & 7;
        int gsw = slot ^ rw;
        u16* Ab = (u16*)(Apart + buf * (128 * 64 * 2));
        const u16* Au = (const u16*)Ag;
        #pragma unroll
        for (int c = 0; c < 4; c++) {
            int r0 = wave * 32 + c * 8;
            gload16_lds(Au + (size_t)(m0 + r0 + rw) * K + kst + gsw * 8, Ab + r0 * 64);
        }
    }
}

// ---------------- 128x128 GEMM, BK=64, counted-vmcnt double-buffer pipeline ----------
// Per K-tile: vmcnt(VM) [tile t landed] -> raw barrier -> swizzled conflict-free
// ds_read_b128 frags -> lgkmcnt(0)+sched_barrier -> raw barrier [reads done] ->
// stage tile t+2 into same buf (async, 2 tiles ahead) -> setprio+32 MFMA.
// Clamped stage index keeps vmcnt counts uniform (tail re-stages never read).
// XCD-bijective tile swizzle (grid sizes are multiples of 8).
// MODE 0: bf16 scatter to [bh][s][dk]; n<1024 -> C0 (scaled by scale0), else C1.
// MODE 1: fp32 row-major [M][1024] -> C0.
// MODE 2: bf16 TRANSPOSED store to Vt[bh][d][s] via wave-private LDS transpose.
template <int AFP32, int MODE>
__global__ __launch_bounds__(256, AFP32 ? 1 : 2) void gemm128(
    const void* __restrict__ Ain, const u16* __restrict__ Bt,
    void* __restrict__ C0p, void* __restrict__ C1p, float scale0) {
    constexpr int ABY = AFP32 ? 128 * 64 * 4 : 128 * 64 * 2;
    constexpr int BBY = 128 * 64 * 2;
    constexpr int NT = DM / 64;  // 16 K-tiles
    __shared__ __align__(16) char smem[2 * ABY + 2 * BBY];
    char* Apart = smem;
    char* Bpart = smem + 2 * ABY;

    // XCD-aware bijective tile swizzle
    int gm = gridDim.x;
    int lin = blockIdx.x + blockIdx.y * gm;
    int cpx = (gm * gridDim.y) >> 3;
    int swz = (lin & 7) * cpx + (lin >> 3);
    int m0 = (swz % gm) * 128;
    int n0 = (swz / gm) * 128;

    int tid = threadIdx.x;
    int lane = tid & 63, wave = tid >> 6;
    int quad = lane >> 4, l15 = lane & 15;
    int wm = wave >> 1, wn = wave & 1;

    f32x4 acc[4][4];
    #pragma unroll
    for (int i = 0; i < 4; i++)
        #pragma unroll
        for (int j = 0; j < 4; j++) acc[i][j] = f32x4{0.f, 0.f, 0.f, 0.f};

    // prologue: stage tiles 0 and 1
    stage_tile<AFP32>(Ain, Bt, Apart, Bpart, 0, 0, m0, n0, wave, lane);
    stage_tile<AFP32>(Ain, Bt, Apart, Bpart, 1, 64, m0, n0, wave, lane);

    for (int t = 0; t < NT; ++t) {
        int buf = t & 1;
        // tile t (staged 2 iters ago) landed: allow only tile t+1's calls in flight
        if constexpr (AFP32)
            asm volatile("s_waitcnt vmcnt(12)" ::: "memory");
        else
            asm volatile("s_waitcnt vmcnt(8)" ::: "memory");
        __builtin_amdgcn_s_barrier();

        // fragment reads (swizzled, conflict-free)
        u16x8 afr[4][2], bfr[4][2];
        {
            const u16* Bb = (const u16*)(Bpart + buf * BBY);
            #pragma unroll
            for (int nt = 0; nt < 4; nt++) {
                const u16* rp = Bb + (wn * 64 + nt * 16 + l15) * 64;
                int sw = l15 & 7;
                bfr[nt][0] = *(const u16x8*)(rp + ((quad ^ sw) << 3));
                bfr[nt][1] = *(const u16x8*)(rp + (((4 + quad) ^ sw) << 3));
            }
        }
        if constexpr (AFP32) {
            const float* Ab = (const float*)(Apart + buf * ABY);
            #pragma unroll
            for (int mt = 0; mt < 4; mt++) {
                const float* rp = Ab + (wm * 64 + mt * 16 + l15) * 64;
                #pragma unroll
                for (int ks = 0; ks < 2; ks++) {
                    int g0 = ks * 8 + quad * 2;
                    f32x4 v0 = *(const f32x4*)(rp + ((g0 ^ l15) << 2));
                    f32x4 v1 = *(const f32x4*)(rp + (((g0 + 1) ^ l15) << 2));
                    u16x8 tt;
                    tt[0] = f2bf(v0[0]); tt[1] = f2bf(v0[1]);
                    tt[2] = f2bf(v0[2]); tt[3] = f2bf(v0[3]);
                    tt[4] = f2bf(v1[0]); tt[5] = f2bf(v1[1]);
                    tt[6] = f2bf(v1[2]); tt[7] = f2bf(v1[3]);
                    afr[mt][ks] = tt;
                }
            }
        } else {
            const u16* Ab = (const u16*)(Apart + buf * ABY);
            #pragma unroll
            for (int mt = 0; mt < 4; mt++) {
                const u16* rp = Ab + (wm * 64 + mt * 16 + l15) * 64;
                int sw = l15 & 7;
                afr[mt][0] = *(const u16x8*)(rp + ((quad ^ sw) << 3));
                afr[mt][1] = *(const u16x8*)(rp + (((4 + quad) ^ sw) << 3));
            }
        }
        // all waves' reads of this buf complete -> safe to overwrite
        asm volatile("s_waitcnt lgkmcnt(0)" ::: "memory");
        __builtin_amdgcn_sched_barrier(0);
        __builtin_amdgcn_s_barrier();

        // stage tile t+2 into the buf just freed (clamped: uniform vmcnt counts)
        int t2 = t + 2;
        if (t2 > NT - 1) t2 = NT - 1;
        stage_tile<AFP32>(Ain, Bt, Apart, Bpart, buf, t2 * 64, m0, n0, wave, lane);

        __builtin_amdgcn_s_setprio(1);
        #pragma unroll
        for (int mt = 0; mt < 4; mt++)
            #pragma unroll
            for (int nt = 0; nt < 4; nt++) {
                acc[mt][nt] = mfma16(afr[mt][0], bfr[nt][0], acc[mt][nt]);
                acc[mt][nt] = mfma16(afr[mt][1], bfr[nt][1], acc[mt][nt]);
            }
        __builtin_amdgcn_s_setprio(0);
    }

    if constexpr (MODE == 2) {
        // wave-private transpose: acc (m,n) -> Ct[wave][n'][m'], then coalesced
        // dwordx4 stores of 8 consecutive s per lane.
        __shared__ u16 Ct[4][64][68];
        #pragma unroll
        for (int mt = 0; mt < 4; mt++)
            #pragma unroll
            for (int nt = 0; nt < 4; nt++)
                #pragma unroll
                for (int r = 0; r < 4; r++) {
                    int mp = mt * 16 + quad * 4 + r;   // s within wave tile
                    int np = nt * 16 + l15;            // d within wave tile
                    Ct[wave][np][mp] = f2bf(acc[mt][nt][r]);
                }
        __syncthreads();
        int bb = m0 >> 11;
        int hh = (n0 + wn * 64) >> 6;                  // one head per wave
        int s_base = (m0 & 2047) + wm * 64;
        u16* Cv = (u16*)C0p;
        #pragma unroll
        for (int c = 0; c < 8; c++) {
            int np = (lane >> 3) + c * 8;              // d row
            int mp = (lane & 7) * 8;                   // 8 consecutive s
            ushort4 lo = *(const ushort4*)(&Ct[wave][np][mp]);
            ushort4 hi = *(const ushort4*)(&Ct[wave][np][mp + 4]);
            u16x8 v;
            v[0] = lo.x; v[1] = lo.y; v[2] = lo.z; v[3] = lo.w;
            v[4] = hi.x; v[5] = hi.y; v[6] = hi.z; v[7] = hi.w;
            size_t addr = ((size_t)(bb * NH + hh) * DK + np) * SEQ + s_base + mp;
            *(u16x8*)(&Cv[addr]) = v;
        }
    } else {
        #pragma unroll
        for (int mt = 0; mt < 4; mt++)
            #pragma unroll
            for (int nt = 0; nt < 4; nt++)
                #pragma unroll
                for (int r = 0; r < 4; r++) {
                    int m = m0 + wm * 64 + mt * 16 + quad * 4 + r;
                    int n = n0 + wn * 64 + nt * 16 + l15;
                    float v = acc[mt][nt][r];
                    if (MODE == 0) {
                        v *= (n < 1024) ? scale0 : 1.0f;
                        u16* C = (n < 1024) ? (u16*)C0p : (u16*)C1p;
                        int ne = n & 1023;
                        int b = m >> 11, s = m & 2047;
                        int h = ne >> 6, d = ne & 63;
                        C[(((size_t)(b * NH + h) * SEQ) + s) * DK + d] = f2bf(v);
                    } else {  // MODE 1
                        ((float*)C0p)[(size_t)m * DM + n] = v;
                    }
                }
    }
}

// ---------------- causal flash attention v7 (do not touch; ~73-79 us) ----------------
// Q pre-scaled by (1/8)*log2(e). K: [bh][s][64]. Vt: [bh][d][s]. Out: [b*SEQ+s][h*64+d] bf16.
// Grid (bh, 16): qs = 15 - blockIdx.y (longest-first); XCD = bh%8 preserved.
// Block = 4 waves x 32 q-rows = 128 q-rows; KV tile 64 keys, double-buffered+swizzled.
// Two independent q-group chains per wave per iteration; 16-MFMA setprio clusters (T5).
// P scratch [4][32][64] XOR-swizzled, stored with f2bf_trunc (P in [0,1]).
// LDS 48 KB -> 3 blocks/CU. Waves 0-1 skip the final (fully-masked) key tile.
__global__ __launch_bounds__(256, 3) void attn_kernel(
    const u16* __restrict__ Qb, const u16* __restrict__ Kb,
    const u16* __restrict__ Vtb, u16* __restrict__ AOb) {
    __shared__ u16 Kl[2][64][64];   // [buf][key][d], swizzled 16B granules
    __shared__ u16 Vl[2][64][64];   // [buf][d][key], swizzled 16B granules
    __shared__ u16 Pl[4][32][64];   // [wave][qrow][key], swizzled 16B granules

    int bh = blockIdx.x;            // 0..63
    int qs = 15 - blockIdx.y;       // longest blocks first
    int q0 = qs * 128;
    int tid = threadIdx.x, lane = tid & 63, wave = tid >> 6;  // wave 0..3
    int quad = lane >> 4, l15 = lane & 15;
    int b = bh >> 4, h = bh & 15;

    const u16* Qg = Qb + (size_t)bh * SEQ * DK;
    const u16* Kg = Kb + (size_t)bh * SEQ * DK;
    const u16* Vg = Vtb + (size_t)bh * DK * SEQ;

    int rw = lane >> 3;             // 0..7: row-within-8 for staging
    int gsw = (lane & 7) ^ rw;      // pre-swizzled source 16B-granule
    int sw8 = l15 & 7;              // row&7 for fragment reads
    u16* Pw = &Pl[wave][0][0];

    // Q fragments: global -> regs; wave owns q rows [32w, 32w+32), 2 groups of 16
    u16x8 aq[2][2];
    for (int g = 0; g < 2; g++)
        for (int kc = 0; kc < 2; kc++)
            aq[g][kc] = *(const u16x8*)(
                &Qg[(size_t)(q0 + wave * 32 + g * 16 + l15) * DK + kc * 32 + quad * 8]);

    float lsum[2][4];
    f32x4 O[2][4];
    for (int g = 0; g < 2; g++)
        for (int r = 0; r < 4; r++) lsum[g][r] = 0.f;
    for (int g = 0; g < 2; g++)
        for (int nt = 0; nt < 4; nt++) O[g][nt] = f32x4{0.f, 0.f, 0.f, 0.f};

    // prologue: stage tile 0 into buf 0
    {
        const u16* gk = &Kg[(size_t)(wave * 16 + rw) * DK + gsw * 8];
        gload16_lds(gk, &Kl[0][wave * 16][0]);
        gload16_lds(gk + 8 * DK, &Kl[0][wave * 16 + 8][0]);
        const u16* gv = &Vg[(size_t)(wave * 16 + rw) * SEQ + gsw * 8];
        gload16_lds(gv, &Vl[0][wave * 16][0]);
        gload16_lds(gv + 8 * SEQ, &Vl[0][wave * 16 + 8][0]);
    }
    __syncthreads();

    int nkt = 2 * qs + 2;                 // key tiles for this q block
    int lastkt = 2 * qs + (wave >> 1);    // this wave's diagonal tile
    int buf = 0;
    for (int kt = 0; kt < nkt; kt++) {
        // issue next tile's loads into buf^1; in flight across compute
        if (kt + 1 < nkt) {
            int k0n = (kt + 1) * 64;
            const u16* gk = &Kg[(size_t)(k0n + wave * 16 + rw) * DK + gsw * 8];
            gload16_lds(gk, &Kl[buf ^ 1][wave * 16][0]);
            gload16_lds(gk + 8 * DK, &Kl[buf ^ 1][wave * 16 + 8][0]);
            const u16* gv = &Vg[(size_t)(wave * 16 + rw) * SEQ + k0n + gsw * 8];
            gload16_lds(gv, &Vl[buf ^ 1][wave * 16][0]);
            gload16_lds(gv + 8 * SEQ, &Vl[buf ^ 1][wave * 16 + 8][0]);
        }

        if (kt <= lastkt) {   // wave-uniform; waves 0-1 skip their fully-masked last tile
            bool diag = (kt == lastkt);
            // S = Q K^T : 16 MFMA (two 16x64 tiles), swizzled conflict-free reads
            f32x4 sc[2][4];
            __builtin_amdgcn_s_setprio(1);
            #pragma unroll
            for (int nt = 0; nt < 4; nt++) {
                const u16* kr = &Kl[buf][nt * 16 + l15][0];
                u16x8 b0 = *(const u16x8*)(kr + (quad ^ sw8) * 8);
                u16x8 b1 = *(const u16x8*)(kr + ((4 + quad) ^ sw8) * 8);
                #pragma unroll
                for (int g = 0; g < 2; g++) {
                    f32x4 z = f32x4{0.f, 0.f, 0.f, 0.f};
                    z = mfma16(aq[g][0], b0, z);
                    z = mfma16(aq[g][1], b1, z);
                    sc[g][nt] = z;
                }
            }
            __builtin_amdgcn_s_setprio(0);
            // P = exp2(S); causal mask only on the wave's diagonal tile
            #pragma unroll
            for (int g = 0; g < 2; g++) {
                if (diag) {
                    #pragma unroll
                    for (int nt = 0; nt < 4; nt++)
                        #pragma unroll
                        for (int r = 0; r < 4; r++) {
                            int qq = q0 + wave * 32 + g * 16 + quad * 4 + r;
                            int kk = kt * 64 + nt * 16 + l15;
                            float e = exp2f(sc[g][nt][r]);
                            float pv = (kk <= qq) ? e : 0.f;
                            sc[g][nt][r] = pv;
                            lsum[g][r] += pv;
                        }
                } else {
                    #pragma unroll
                    for (int nt = 0; nt < 4; nt++)
                        #pragma unroll
                        for (int r = 0; r < 4; r++) {
                            float pv = exp2f(sc[g][nt][r]);
                            sc[g][nt][r] = pv;
                            lsum[g][r] += pv;
                        }
                }
                // P -> wave-private swizzled LDS slice; truncating cvt
                #pragma unroll
                for (int nt = 0; nt < 4; nt++)
                    #pragma unroll
                    for (int r = 0; r < 4; r++) {
                        int prow = g * 16 + quad * 4 + r;
                        int pcol = nt * 16 + l15;
                        int scol = (((pcol >> 3) ^ (prow & 7)) << 3) | (pcol & 7);
                        Pw[prow * 64 + scol] = f2bf_trunc(sc[g][nt][r]);
                    }
            }
            // O += P V : 16 MFMA
            u16x8 ap[2][2];
            #pragma unroll
            for (int g = 0; g < 2; g++)
                #pragma unroll
                for (int kc = 0; kc < 2; kc++)
                    ap[g][kc] = *(const u16x8*)(
                        &Pw[(g * 16 + l15) * 64 + (((kc * 4 + quad) ^ sw8) << 3)]);
            __builtin_amdgcn_s_setprio(1);
            #pragma unroll
            for (int nt = 0; nt < 4; nt++) {
                const u16* vr = &Vl[buf][nt * 16 + l15][0];
                u16x8 b0 = *(const u16x8*)(vr + (quad ^ sw8) * 8);
                u16x8 b1 = *(const u16x8*)(vr + ((4 + quad) ^ sw8) * 8);
                #pragma unroll
                for (int g = 0; g < 2; g++) {
                    O[g][nt] = mfma16(ap[g][0], b0, O[g][nt]);
                    O[g][nt] = mfma16(ap[g][1], b1, O[g][nt]);
                }
            }
            __builtin_amdgcn_s_setprio(0);
        }
        __syncthreads();  // drains vmcnt (next tile staged) + all buf reads done
        buf ^= 1;
    }

    // epilogue: reduce lsum across the 16 column lanes, normalize, store
    #pragma unroll
    for (int g = 0; g < 2; g++)
        #pragma unroll
        for (int r = 0; r < 4; r++) {
            float s = lsum[g][r];
            for (int off = 1; off < 16; off <<= 1) s += __shfl_xor(s, off, 64);
            float inv = 1.0f / s;
            int q = q0 + wave * 32 + g * 16 + quad * 4 + r;
            #pragma unroll
            for (int nt = 0; nt < 4; nt++) {
                int d = nt * 16 + l15;
                AOb[((size_t)(b * SEQ + q)) * DM + h * DK + d] = f2bf(O[g][nt][r] * inv);
            }
        }
}

extern "C" void kernel_launch(void* const* d_in, const int* in_sizes, int n_in,
                              void* d_out, int out_size, void* d_ws, size_t ws_size,
                              hipStream_t stream) {
    const float* x = (const float*)d_in[0];
    const float* Wq = (const float*)d_in[1];
    const float* Wk = (const float*)d_in[2];
    const float* Wv = (const float*)d_in[3];
    const float* Wo = (const float*)d_in[4];
    float* out = (float*)d_out;

    // Regions: ws = S0|S1 (16 MB each), d_out = D0|D1 (16 MB each).
    // 1. cvt x -> xb@S0
    // 2. T(Wq,Wk) -> wqk@D0 head (4 MB)
    // 3. gemmQK(xb, wqk) -> Q@S1 (scaled), K@D1
    // 4. T(Wv) -> wvt@S0 head (xb dead: V-GEMM reads fp32 x directly)
    // 5. gemmV MODE2 (x fp32, wvt) -> Vt@D0 [bh][d][s] (overwrites wqk head)
    // 6. attn(Q@S1, K@D1, Vt@D0) -> AO@S0 (over dead wvt/xb)
    // 7. T(Wo) -> wot@S1 head (Q dead)
    // 8. gemmO(AO@S0, wot@S1h) -> d_out fp32 (D0+D1; Vt,K dead)
    const size_t HALF = (size_t)M_TOT * DM * 2;  // 16 MB
    char* S0 = (char*)d_ws;
    char* S1 = (char*)d_ws + HALF;
    char* D0 = (char*)d_out;
    char* D1 = (char*)d_out + HALF;

    u16* xb  = (u16*)S0;
    u16* Qb  = (u16*)S1;
    u16* Kb  = (u16*)D1;
    u16* Vt  = (u16*)D0;
    u16* AOb = (u16*)S0;
    u16* wqk = (u16*)D0;   // 4 MB
    u16* wvt = (u16*)S0;   // 2 MB over dead xb
    u16* wot = (u16*)S1;   // 2 MB over dead Q

    const float cscale = 0.125f * 1.44269504088896f;  // 1/sqrt(64) * log2(e)
    dim3 tg2(32, 32, 2);
    dim3 tg1(32, 32, 1);
    dim3 gg(M_TOT / 128, DM / 128);

    // 1) x -> bf16
    int n4 = M_TOT * DM / 4;
    cvt_bf16_kernel<<<n4 / 256, 256, 0, stream>>>(x, xb, n4);

    // 2-3) fused Q,K projection (Q pre-scaled)
    transpose_w_kernel<<<tg2, 256, 0, stream>>>(Wq, Wk, wqk);
    dim3 gqk(M_TOT / 128, 2048 / 128);
    gemm128<0, 0><<<gqk, 256, 0, stream>>>(xb, wqk, (void*)Qb, (void*)Kb, cscale);

    // 4-5) V projection with fused transpose (fp32 A from d_in)
    transpose_w_kernel<<<tg1, 256, 0, stream>>>(Wv, Wv, wvt);
    gemm128<1, 2><<<gg, 256, 0, stream>>>(x, wvt, (void*)Vt, (void*)Vt, 1.0f);

    // 6) attention
    dim3 ag(BH, 16);
    attn_kernel<<<ag, 256, 0, stream>>>(Qb, Kb, Vt, AOb);

    // 7-8) output projection straight into d_out
    transpose_w_kernel<<<tg1, 256, 0, stream>>>(Wo, Wo, wot);
    gemm128<0, 1><<<gg, 256, 0, stream>>>(AOb, wot, (void*)out, (void*)out, 1.0f);
}

// Round 7
// 270.550 us; speedup vs baseline: 1.0270x; 1.0270x over previous
//
#include <hip/hip_runtime.h>
#include <hip/hip_bf16.h>
#include <stdint.h>

#define B_SZ 4
#define SEQ 2048
#define DM 1024
#define NH 16
#define DK 64
#define BH (B_SZ * NH)      // 64
#define M_TOT (B_SZ * SEQ)  // 8192

typedef unsigned short u16;
typedef u16 u16x8 __attribute__((ext_vector_type(8)));
typedef __bf16 bf16x8 __attribute__((ext_vector_type(8)));
typedef float f32x4 __attribute__((ext_vector_type(4)));

// native RNE fp32->bf16 (single v_cvt instr on gfx950)
__device__ __forceinline__ u16 f2bf(float f) {
    return __builtin_bit_cast(u16, (__bf16)f);
}

// truncating fp32->bf16 (1 shift; used only for P in [0,1] -- v7-verified)
__device__ __forceinline__ u16 f2bf_trunc(float f) {
    union { float f; uint32_t u; } v; v.f = f;
    return (u16)(v.u >> 16);
}

__device__ __forceinline__ f32x4 mfma16(u16x8 a, u16x8 b, f32x4 c) {
    return __builtin_amdgcn_mfma_f32_16x16x32_bf16(
        __builtin_bit_cast(bf16x8, a), __builtin_bit_cast(bf16x8, b), c, 0, 0, 0);
}

// async global->LDS, 16 B per lane; lds dest = wave-uniform base + lane*16
__device__ __forceinline__ void gload16_lds(const void* g, void* l) {
    __builtin_amdgcn_global_load_lds(
        (const __attribute__((address_space(1))) void*)(uintptr_t)g,
        (__attribute__((address_space(3))) void*)(uintptr_t)l, 16, 0, 0);
}

// ---------------- x fp32 -> bf16 ----------------
__global__ void cvt_bf16_kernel(const float* __restrict__ in, u16* __restrict__ out, int n4) {
    int i = blockIdx.x * blockDim.x + threadIdx.x;
    if (i < n4) {
        float4 v = ((const float4*)in)[i];
        ushort4 o;
        o.x = f2bf(v.x); o.y = f2bf(v.y); o.z = f2bf(v.z); o.w = f2bf(v.w);
        ((ushort4*)out)[i] = o;
    }
}

// ---------------- W [K][N] fp32 -> Wt [N][K] bf16 (z = weight index) ----------------
__global__ void transpose_w_kernel(const float* __restrict__ W0, const float* __restrict__ W1,
                                   u16* __restrict__ Wt) {
    __shared__ u16 tile[32][33];
    int bx = blockIdx.x, by = blockIdx.y, z = blockIdx.z;
    const float* W = z ? W1 : W0;
    u16* Wd = Wt + (size_t)z * DM * DM;
    int t = threadIdx.x;
    for (int i = 0; i < 4; i++) {
        int idx = t + i * 256;
        int r = idx >> 5, c = idx & 31;
        tile[r][c] = f2bf(W[(by * 32 + r) * DM + bx * 32 + c]);
    }
    __syncthreads();
    for (int i = 0; i < 4; i++) {
        int idx = t + i * 256;
        int r2 = idx >> 5, c2 = idx & 31;
        Wd[(bx * 32 + r2) * DM + by * 32 + c2] = tile[c2][r2];
    }
}

// ---------------- 256x128 bf16 GEMM, BK=64, counted-vmcnt double-buffer -------------
// R6-verified skeleton scaled to 256x128 / 8 waves (catalog: tile size gates the
// counted-vmcnt gain; 128^2+2ph is flat, 256-class+2ph ~680 TF).
// Per K-tile: vmcnt(6) [tile t landed; only t+1's 6 calls in flight] -> s_barrier ->
// swizzled ds_read_b128 frags (2-way max = free) -> lgkmcnt(0)+sched_barrier ->
// s_barrier [all reads done -> buf free] -> stage tile t+2 (6 calls, clamped tail) ->
// setprio + 32 MFMA. LDS 96 KB -> 1 block/CU, 8 waves (2/SIMD).
// MODE 0: bf16 scatter to [bh][s][dk]; n<1024 -> C0 (scaled by scale0), else C1.
// MODE 1: fp32 row-major [M][1024] -> C0.
template <int MODE>
__global__ __launch_bounds__(512, 2) void gemm256(
    const u16* __restrict__ Ain, const u16* __restrict__ Bt,
    void* __restrict__ C0p, void* __restrict__ C1p, float scale0) {
    constexpr int NT = DM / 64;  // 16 K-tiles
    __shared__ __align__(16) u16 As[2 * 256 * 64];
    __shared__ __align__(16) u16 Bs[2 * 128 * 64];

    // XCD-aware bijective tile swizzle (grid size multiple of 8)
    int gm = gridDim.x;
    int lin = blockIdx.x + blockIdx.y * gm;
    int cpx = (gm * gridDim.y) >> 3;
    int swz = (lin & 7) * cpx + (lin >> 3);
    int m0 = (swz % gm) * 256;
    int n0 = (swz / gm) * 128;

    int tid = threadIdx.x;
    int lane = tid & 63, wave = tid >> 6;       // 0..7
    int quad = lane >> 4, l15 = lane & 15;
    int wm = wave >> 1, wn = wave & 1;          // 4M x 2N wave grid

    int rw = lane >> 3;            // 0..7: row within 8-row staging group
    int gsw = (lane & 7) ^ rw;     // pre-swizzled source 16B-granule (involution)

    f32x4 acc[4][4];
    #pragma unroll
    for (int i = 0; i < 4; i++)
        #pragma unroll
        for (int j = 0; j < 4; j++) acc[i][j] = f32x4{0.f, 0.f, 0.f, 0.f};

    // stage one 256x64 A-tile (4 calls) + 128x64 B-tile (2 calls) into buf
    auto stage = [&](int buf, int kst) {
        const u16* ga = Ain + (size_t)(m0 + wave * 32 + rw) * DM + kst + gsw * 8;
        u16* la = As + buf * (256 * 64) + (wave * 32) * 64;
        #pragma unroll
        for (int c = 0; c < 4; c++)
            gload16_lds(ga + (size_t)(c * 8) * DM, la + c * 8 * 64);
        const u16* gb = Bt + (size_t)(n0 + wave * 16 + rw) * DM + kst + gsw * 8;
        u16* lb = Bs + buf * (128 * 64) + (wave * 16) * 64;
        gload16_lds(gb, lb);
        gload16_lds(gb + (size_t)8 * DM, lb + 8 * 64);
    };

    // prologue: tiles 0 and 1 in flight (12 calls)
    stage(0, 0);
    stage(1, 64);

    int sw = l15 & 7;   // row&7 for fragment reads (row offsets are multiples of 16)
    for (int t = 0; t < NT; ++t) {
        int buf = t & 1;
        // tile t landed (only tile t+1's 6 calls may remain in flight)
        asm volatile("s_waitcnt vmcnt(6)" ::: "memory");
        __builtin_amdgcn_s_barrier();

        u16x8 afr[4][2], bfr[4][2];
        {
            const u16* Ab = As + buf * (256 * 64);
            #pragma unroll
            for (int mt = 0; mt < 4; mt++) {
                const u16* rp = Ab + (wm * 64 + mt * 16 + l15) * 64;
                afr[mt][0] = *(const u16x8*)(rp + ((quad ^ sw) << 3));
                afr[mt][1] = *(const u16x8*)(rp + (((4 + quad) ^ sw) << 3));
            }
            const u16* Bb = Bs + buf * (128 * 64);
            #pragma unroll
            for (int nt = 0; nt < 4; nt++) {
                const u16* rp = Bb + (wn * 64 + nt * 16 + l15) * 64;
                bfr[nt][0] = *(const u16x8*)(rp + ((quad ^ sw) << 3));
                bfr[nt][1] = *(const u16x8*)(rp + (((4 + quad) ^ sw) << 3));
            }
        }
        // all waves' reads of this buf complete -> safe to overwrite
        asm volatile("s_waitcnt lgkmcnt(0)" ::: "memory");
        __builtin_amdgcn_sched_barrier(0);
        __builtin_amdgcn_s_barrier();

        // stage tile t+2 into the freed buf (clamped: tail re-stages never read)
        int t2 = t + 2;
        if (t2 > NT - 1) t2 = NT - 1;
        stage(buf, t2 * 64);

        __builtin_amdgcn_s_setprio(1);
        #pragma unroll
        for (int mt = 0; mt < 4; mt++)
            #pragma unroll
            for (int nt = 0; nt < 4; nt++) {
                acc[mt][nt] = mfma16(afr[mt][0], bfr[nt][0], acc[mt][nt]);
                acc[mt][nt] = mfma16(afr[mt][1], bfr[nt][1], acc[mt][nt]);
            }
        __builtin_amdgcn_s_setprio(0);
    }

    #pragma unroll
    for (int mt = 0; mt < 4; mt++)
        #pragma unroll
        for (int nt = 0; nt < 4; nt++)
            #pragma unroll
            for (int r = 0; r < 4; r++) {
                int m = m0 + wm * 64 + mt * 16 + quad * 4 + r;
                int n = n0 + wn * 64 + nt * 16 + l15;
                float v = acc[mt][nt][r];
                if (MODE == 0) {
                    v *= (n < 1024) ? scale0 : 1.0f;
                    u16* C = (n < 1024) ? (u16*)C0p : (u16*)C1p;
                    int ne = n & 1023;
                    int b = m >> 11, s = m & 2047;
                    int h = ne >> 6, d = ne & 63;
                    C[(((size_t)(b * NH + h) * SEQ) + s) * DK + d] = f2bf(v);
                } else {  // MODE 1
                    ((float*)C0p)[(size_t)m * DM + n] = v;
                }
            }
}

// ---------------- V-GEMM: 128x128x32, fp32 A, LDS-transpose epilogue (R5-verified) --
// Reads fp32 x directly; writes Vt[bh][d][s] via wave-private LDS transpose
// (coalesced dwordx4 stores).
__global__ __launch_bounds__(256, 2) void gemm_v(
    const float* __restrict__ Ain, const u16* __restrict__ Bt,
    u16* __restrict__ C0p) {
    __shared__ u16 As[128][32];
    __shared__ u16 Bs[128][32];
    const int K = DM;
    int m0 = blockIdx.x * 128;
    int n0 = blockIdx.y * 128;
    int tid = threadIdx.x;
    int lane = tid & 63, wave = tid >> 6;
    int quad = lane >> 4, l15 = lane & 15;
    int wm = wave >> 1, wn = wave & 1;

    f32x4 acc[4][4];
    for (int i = 0; i < 4; i++)
        for (int j = 0; j < 4; j++) acc[i][j] = f32x4{0.f, 0.f, 0.f, 0.f};

    int rS = lane >> 2;
    int cS = (lane & 3) * 8;

    for (int k0 = 0; k0 < K; k0 += 32) {
        __syncthreads();
        for (int i = 0; i < 4; i++) {
            int idx = tid + i * 256;
            int r = idx >> 3, c = (idx & 7) * 4;
            float4 v = *(const float4*)(&Ain[(size_t)(m0 + r) * K + k0 + c]);
            ushort4 o;
            o.x = f2bf(v.x); o.y = f2bf(v.y); o.z = f2bf(v.z); o.w = f2bf(v.w);
            *(ushort4*)(&As[r][c]) = o;
        }
        {
            const u16* gb = &Bt[(size_t)(n0 + wave * 32 + rS) * K + k0 + cS];
            gload16_lds(gb, &Bs[wave * 32][0]);
            gload16_lds(gb + (size_t)16 * K, &Bs[wave * 32 + 16][0]);
        }
        __syncthreads();
        u16x8 af[4], bfv[4];
        for (int mt = 0; mt < 4; mt++)
            af[mt] = *(const u16x8*)(&As[wm * 64 + mt * 16 + l15][quad * 8]);
        for (int nt = 0; nt < 4; nt++)
            bfv[nt] = *(const u16x8*)(&Bs[wn * 64 + nt * 16 + l15][quad * 8]);
        for (int mt = 0; mt < 4; mt++)
            for (int nt = 0; nt < 4; nt++)
                acc[mt][nt] = mfma16(af[mt], bfv[nt], acc[mt][nt]);
    }

    // wave-private transpose epilogue -> coalesced stores to Vt[bh][d][s]
    __shared__ u16 Ct[4][64][68];
    #pragma unroll
    for (int mt = 0; mt < 4; mt++)
        #pragma unroll
        for (int nt = 0; nt < 4; nt++)
            #pragma unroll
            for (int r = 0; r < 4; r++) {
                int mp = mt * 16 + quad * 4 + r;   // s within wave tile
                int np = nt * 16 + l15;            // d within wave tile
                Ct[wave][np][mp] = f2bf(acc[mt][nt][r]);
            }
    __syncthreads();
    int bb = m0 >> 11;
    int hh = (n0 + wn * 64) >> 6;                  // one head per wave
    int s_base = (m0 & 2047) + wm * 64;
    #pragma unroll
    for (int c = 0; c < 8; c++) {
        int np = (lane >> 3) + c * 8;              // d row
        int mp = (lane & 7) * 8;                   // 8 consecutive s
        ushort4 lo = *(const ushort4*)(&Ct[wave][np][mp]);
        ushort4 hi = *(const ushort4*)(&Ct[wave][np][mp + 4]);
        u16x8 v;
        v[0] = lo.x; v[1] = lo.y; v[2] = lo.z; v[3] = lo.w;
        v[4] = hi.x; v[5] = hi.y; v[6] = hi.z; v[7] = hi.w;
        size_t addr = ((size_t)(bb * NH + hh) * DK + np) * SEQ + s_base + mp;
        *(u16x8*)(&C0p[addr]) = v;
    }
}

// ---------------- causal flash attention v7 (do not touch; ~73-81 us) ----------------
// Q pre-scaled by (1/8)*log2(e). K: [bh][s][64]. Vt: [bh][d][s]. Out: [b*SEQ+s][h*64+d] bf16.
// Grid (bh, 16): qs = 15 - blockIdx.y (longest-first); XCD = bh%8 preserved.
// Block = 4 waves x 32 q-rows = 128 q-rows; KV tile 64 keys, double-buffered+swizzled.
// Two independent q-group chains per wave per iteration; 16-MFMA setprio clusters (T5).
// P scratch [4][32][64] XOR-swizzled, stored with f2bf_trunc (P in [0,1]).
// LDS 48 KB -> 3 blocks/CU. Waves 0-1 skip the final (fully-masked) key tile.
__global__ __launch_bounds__(256, 3) void attn_kernel(
    const u16* __restrict__ Qb, const u16* __restrict__ Kb,
    const u16* __restrict__ Vtb, u16* __restrict__ AOb) {
    __shared__ u16 Kl[2][64][64];   // [buf][key][d], swizzled 16B granules
    __shared__ u16 Vl[2][64][64];   // [buf][d][key], swizzled 16B granules
    __shared__ u16 Pl[4][32][64];   // [wave][qrow][key], swizzled 16B granules

    int bh = blockIdx.x;            // 0..63
    int qs = 15 - blockIdx.y;       // longest blocks first
    int q0 = qs * 128;
    int tid = threadIdx.x, lane = tid & 63, wave = tid >> 6;  // wave 0..3
    int quad = lane >> 4, l15 = lane & 15;
    int b = bh >> 4, h = bh & 15;

    const u16* Qg = Qb + (size_t)bh * SEQ * DK;
    const u16* Kg = Kb + (size_t)bh * SEQ * DK;
    const u16* Vg = Vtb + (size_t)bh * DK * SEQ;

    int rw = lane >> 3;             // 0..7: row-within-8 for staging
    int gsw = (lane & 7) ^ rw;      // pre-swizzled source 16B-granule
    int sw8 = l15 & 7;              // row&7 for fragment reads
    u16* Pw = &Pl[wave][0][0];

    // Q fragments: global -> regs; wave owns q rows [32w, 32w+32), 2 groups of 16
    u16x8 aq[2][2];
    for (int g = 0; g < 2; g++)
        for (int kc = 0; kc < 2; kc++)
            aq[g][kc] = *(const u16x8*)(
                &Qg[(size_t)(q0 + wave * 32 + g * 16 + l15) * DK + kc * 32 + quad * 8]);

    float lsum[2][4];
    f32x4 O[2][4];
    for (int g = 0; g < 2; g++)
        for (int r = 0; r < 4; r++) lsum[g][r] = 0.f;
    for (int g = 0; g < 2; g++)
        for (int nt = 0; nt < 4; nt++) O[g][nt] = f32x4{0.f, 0.f, 0.f, 0.f};

    // prologue: stage tile 0 into buf 0
    {
        const u16* gk = &Kg[(size_t)(wave * 16 + rw) * DK + gsw * 8];
        gload16_lds(gk, &Kl[0][wave * 16][0]);
        gload16_lds(gk + 8 * DK, &Kl[0][wave * 16 + 8][0]);
        const u16* gv = &Vg[(size_t)(wave * 16 + rw) * SEQ + gsw * 8];
        gload16_lds(gv, &Vl[0][wave * 16][0]);
        gload16_lds(gv + 8 * SEQ, &Vl[0][wave * 16 + 8][0]);
    }
    __syncthreads();

    int nkt = 2 * qs + 2;                 // key tiles for this q block
    int lastkt = 2 * qs + (wave >> 1);    // this wave's diagonal tile
    int buf = 0;
    for (int kt = 0; kt < nkt; kt++) {
        // issue next tile's loads into buf^1; in flight across compute
        if (kt + 1 < nkt) {
            int k0n = (kt + 1) * 64;
            const u16* gk = &Kg[(size_t)(k0n + wave * 16 + rw) * DK + gsw * 8];
            gload16_lds(gk, &Kl[buf ^ 1][wave * 16][0]);
            gload16_lds(gk + 8 * DK, &Kl[buf ^ 1][wave * 16 + 8][0]);
            const u16* gv = &Vg[(size_t)(wave * 16 + rw) * SEQ + k0n + gsw * 8];
            gload16_lds(gv, &Vl[buf ^ 1][wave * 16][0]);
            gload16_lds(gv + 8 * SEQ, &Vl[buf ^ 1][wave * 16 + 8][0]);
        }

        if (kt <= lastkt) {   // wave-uniform; waves 0-1 skip their fully-masked last tile
            bool diag = (kt == lastkt);
            // S = Q K^T : 16 MFMA (two 16x64 tiles), swizzled conflict-free reads
            f32x4 sc[2][4];
            __builtin_amdgcn_s_setprio(1);
            #pragma unroll
            for (int nt = 0; nt < 4; nt++) {
                const u16* kr = &Kl[buf][nt * 16 + l15][0];
                u16x8 b0 = *(const u16x8*)(kr + (quad ^ sw8) * 8);
                u16x8 b1 = *(const u16x8*)(kr + ((4 + quad) ^ sw8) * 8);
                #pragma unroll
                for (int g = 0; g < 2; g++) {
                    f32x4 z = f32x4{0.f, 0.f, 0.f, 0.f};
                    z = mfma16(aq[g][0], b0, z);
                    z = mfma16(aq[g][1], b1, z);
                    sc[g][nt] = z;
                }
            }
            __builtin_amdgcn_s_setprio(0);
            // P = exp2(S); causal mask only on the wave's diagonal tile
            #pragma unroll
            for (int g = 0; g < 2; g++) {
                if (diag) {
                    #pragma unroll
                    for (int nt = 0; nt < 4; nt++)
                        #pragma unroll
                        for (int r = 0; r < 4; r++) {
                            int qq = q0 + wave * 32 + g * 16 + quad * 4 + r;
                            int kk = kt * 64 + nt * 16 + l15;
                            float e = exp2f(sc[g][nt][r]);
                            float pv = (kk <= qq) ? e : 0.f;
                            sc[g][nt][r] = pv;
                            lsum[g][r] += pv;
                        }
                } else {
                    #pragma unroll
                    for (int nt = 0; nt < 4; nt++)
                        #pragma unroll
                        for (int r = 0; r < 4; r++) {
                            float pv = exp2f(sc[g][nt][r]);
                            sc[g][nt][r] = pv;
                            lsum[g][r] += pv;
                        }
                }
                // P -> wave-private swizzled LDS slice; truncating cvt
                #pragma unroll
                for (int nt = 0; nt < 4; nt++)
                    #pragma unroll
                    for (int r = 0; r < 4; r++) {
                        int prow = g * 16 + quad * 4 + r;
                        int pcol = nt * 16 + l15;
                        int scol = (((pcol >> 3) ^ (prow & 7)) << 3) | (pcol & 7);
                        Pw[prow * 64 + scol] = f2bf_trunc(sc[g][nt][r]);
                    }
            }
            // O += P V : 16 MFMA
            u16x8 ap[2][2];
            #pragma unroll
            for (int g = 0; g < 2; g++)
                #pragma unroll
                for (int kc = 0; kc < 2; kc++)
                    ap[g][kc] = *(const u16x8*)(
                        &Pw[(g * 16 + l15) * 64 + (((kc * 4 + quad) ^ sw8) << 3)]);
            __builtin_amdgcn_s_setprio(1);
            #pragma unroll
            for (int nt = 0; nt < 4; nt++) {
                const u16* vr = &Vl[buf][nt * 16 + l15][0];
                u16x8 b0 = *(const u16x8*)(vr + (quad ^ sw8) * 8);
                u16x8 b1 = *(const u16x8*)(vr + ((4 + quad) ^ sw8) * 8);
                #pragma unroll
                for (int g = 0; g < 2; g++) {
                    O[g][nt] = mfma16(ap[g][0], b0, O[g][nt]);
                    O[g][nt] = mfma16(ap[g][1], b1, O[g][nt]);
                }
            }
            __builtin_amdgcn_s_setprio(0);
        }
        __syncthreads();  // drains vmcnt (next tile staged) + all buf reads done
        buf ^= 1;
    }

    // epilogue: reduce lsum across the 16 column lanes, normalize, store
    #pragma unroll
    for (int g = 0; g < 2; g++)
        #pragma unroll
        for (int r = 0; r < 4; r++) {
            float s = lsum[g][r];
            for (int off = 1; off < 16; off <<= 1) s += __shfl_xor(s, off, 64);
            float inv = 1.0f / s;
            int q = q0 + wave * 32 + g * 16 + quad * 4 + r;
            #pragma unroll
            for (int nt = 0; nt < 4; nt++) {
                int d = nt * 16 + l15;
                AOb[((size_t)(b * SEQ + q)) * DM + h * DK + d] = f2bf(O[g][nt][r] * inv);
            }
        }
}

extern "C" void kernel_launch(void* const* d_in, const int* in_sizes, int n_in,
                              void* d_out, int out_size, void* d_ws, size_t ws_size,
                              hipStream_t stream) {
    const float* x = (const float*)d_in[0];
    const float* Wq = (const float*)d_in[1];
    const float* Wk = (const float*)d_in[2];
    const float* Wv = (const float*)d_in[3];
    const float* Wo = (const float*)d_in[4];
    float* out = (float*)d_out;

    // Regions: ws = S0|S1 (16 MB each), d_out = D0|D1 (16 MB each).
    // 1. cvt x -> xb@S0
    // 2. T(Wq,Wk) -> wqk@D0 head (4 MB)
    // 3. gemm256<0>(xb, wqk) -> Q@S1 (scaled), K@D1
    // 4. T(Wv) -> wvt@S0 head (xb dead: V-GEMM reads fp32 x directly)
    // 5. gemm_v(x fp32, wvt) -> Vt@D0 [bh][d][s] (overwrites wqk head)
    // 6. attn(Q@S1, K@D1, Vt@D0) -> AO@S0 (over dead wvt/xb)
    // 7. T(Wo) -> wot@S1 head (Q dead)
    // 8. gemm256<1>(AO@S0, wot@S1h) -> d_out fp32 (D0+D1; Vt,K dead)
    const size_t HALF = (size_t)M_TOT * DM * 2;  // 16 MB
    char* S0 = (char*)d_ws;
    char* S1 = (char*)d_ws + HALF;
    char* D0 = (char*)d_out;
    char* D1 = (char*)d_out + HALF;

    u16* xb  = (u16*)S0;
    u16* Qb  = (u16*)S1;
    u16* Kb  = (u16*)D1;
    u16* Vt  = (u16*)D0;
    u16* AOb = (u16*)S0;
    u16* wqk = (u16*)D0;   // 4 MB
    u16* wvt = (u16*)S0;   // 2 MB over dead xb
    u16* wot = (u16*)S1;   // 2 MB over dead Q

    const float cscale = 0.125f * 1.44269504088896f;  // 1/sqrt(64) * log2(e)
    dim3 tg2(32, 32, 2);
    dim3 tg1(32, 32, 1);

    // 1) x -> bf16
    int n4 = M_TOT * DM / 4;
    cvt_bf16_kernel<<<n4 / 256, 256, 0, stream>>>(x, xb, n4);

    // 2-3) fused Q,K projection (Q pre-scaled), 256x128 tiles
    transpose_w_kernel<<<tg2, 256, 0, stream>>>(Wq, Wk, wqk);
    dim3 gqk(M_TOT / 256, 2048 / 128);   // 32 x 16 = 512 blocks
    gemm256<0><<<gqk, 512, 0, stream>>>(xb, wqk, (void*)Qb, (void*)Kb, cscale);

    // 4-5) V projection with fused transpose (fp32 A from d_in)
    transpose_w_kernel<<<tg1, 256, 0, stream>>>(Wv, Wv, wvt);
    dim3 gv(M_TOT / 128, DM / 128);      // 64 x 8
    gemm_v<<<gv, 256, 0, stream>>>(x, wvt, Vt);

    // 6) attention
    dim3 ag(BH, 16);
    attn_kernel<<<ag, 256, 0, stream>>>(Qb, Kb, Vt, AOb);

    // 7-8) output projection straight into d_out, 256x128 tiles
    transpose_w_kernel<<<tg1, 256, 0, stream>>>(Wo, Wo, wot);
    dim3 go(M_TOT / 256, DM / 128);      // 32 x 8 = 256 blocks
    gemm256<1><<<go, 512, 0, stream>>>(AOb, wot, (void*)out, (void*)out, 1.0f);
}

// Round 8
// 264.866 us; speedup vs baseline: 1.0491x; 1.0215x over previous
//
#include <hip/hip_runtime.h>
#include <hip/hip_bf16.h>
#include <stdint.h>

#define B_SZ 4
#define SEQ 2048
#define DM 1024
#define NH 16
#define DK 64
#define BH (B_SZ * NH)      // 64
#define M_TOT (B_SZ * SEQ)  // 8192

typedef unsigned short u16;
typedef u16 u16x8 __attribute__((ext_vector_type(8)));
typedef __bf16 bf16x8 __attribute__((ext_vector_type(8)));
typedef float f32x4 __attribute__((ext_vector_type(4)));

// native RNE fp32->bf16 (single v_cvt instr on gfx950)
__device__ __forceinline__ u16 f2bf(float f) {
    return __builtin_bit_cast(u16, (__bf16)f);
}

// truncating fp32->bf16 (1 shift; used only for P in [0,1] -- v7-verified)
__device__ __forceinline__ u16 f2bf_trunc(float f) {
    union { float f; uint32_t u; } v; v.f = f;
    return (u16)(v.u >> 16);
}

__device__ __forceinline__ f32x4 mfma16(u16x8 a, u16x8 b, f32x4 c) {
    return __builtin_amdgcn_mfma_f32_16x16x32_bf16(
        __builtin_bit_cast(bf16x8, a), __builtin_bit_cast(bf16x8, b), c, 0, 0, 0);
}

// async global->LDS, 16 B per lane; lds dest = wave-uniform base + lane*16
__device__ __forceinline__ void gload16_lds(const void* g, void* l) {
    __builtin_amdgcn_global_load_lds(
        (const __attribute__((address_space(1))) void*)(uintptr_t)g,
        (__attribute__((address_space(3))) void*)(uintptr_t)l, 16, 0, 0);
}

// ---------------- x fp32 -> bf16 ----------------
__global__ void cvt_bf16_kernel(const float* __restrict__ in, u16* __restrict__ out, int n4) {
    int i = blockIdx.x * blockDim.x + threadIdx.x;
    if (i < n4) {
        float4 v = ((const float4*)in)[i];
        ushort4 o;
        o.x = f2bf(v.x); o.y = f2bf(v.y); o.z = f2bf(v.z); o.w = f2bf(v.w);
        ((ushort4*)out)[i] = o;
    }
}

// ---------------- W [K][N] fp32 -> Wt [N][K] bf16 (z = weight index) ----------------
__global__ void transpose_w_kernel(const float* __restrict__ W0, const float* __restrict__ W1,
                                   u16* __restrict__ Wt) {
    __shared__ u16 tile[32][33];
    int bx = blockIdx.x, by = blockIdx.y, z = blockIdx.z;
    const float* W = z ? W1 : W0;
    u16* Wd = Wt + (size_t)z * DM * DM;
    int t = threadIdx.x;
    for (int i = 0; i < 4; i++) {
        int idx = t + i * 256;
        int r = idx >> 5, c = idx & 31;
        tile[r][c] = f2bf(W[(by * 32 + r) * DM + bx * 32 + c]);
    }
    __syncthreads();
    for (int i = 0; i < 4; i++) {
        int idx = t + i * 256;
        int r2 = idx >> 5, c2 = idx & 31;
        Wd[(bx * 32 + r2) * DM + by * 32 + c2] = tile[c2][r2];
    }
}

// L2-supertile XCD scheduling (pure bijective block reorder; no numeric effect).
// Assumes round-robin dispatch xcd = wgid%8. Each XCD's resident 32 blocks form
// one 4(m) x 8(n) supertile: 4 A-panels + 8 B-panels ~= 4 MB <= per-XCD L2, so
// panel re-reads hit L2 instead of HBM (GEMMs measured staging-traffic-bound:
// ~1.04 GB staged / 6.3 TB/s ~= the observed ~175 us GEMM time).
__device__ __forceinline__ void supertile_bxby(int gm, int* bxp, int* byp) {
    int wg = blockIdx.x + blockIdx.y * gm;
    int j = (wg >> 3) & 31;                 // slot within supertile
    int s = (wg & 7) + ((wg >> 8) << 3);    // supertile id = xcd + 8*round
    int sxc = gm >> 2;                      // supertiles along m
    *bxp = (s % sxc) * 4 + (j & 3);
    *byp = (s / sxc) * 8 + (j >> 2);
}

// ---------------- 256x128 bf16 GEMM, BK=64, counted-vmcnt double-buffer -------------
// R6/R7-verified skeleton. Per K-tile: vmcnt(6) [tile t landed] -> s_barrier ->
// swizzled ds_read_b128 frags (2-way max = free) -> lgkmcnt(0)+sched_barrier ->
// s_barrier [buf free] -> stage tile t+2 (6 calls, clamped tail) -> setprio+32 MFMA.
// LDS 96 KB -> 1 block/CU, 8 waves.
// MODE 0: bf16 scatter to [bh][s][dk]; n<1024 -> C0 (scaled by scale0), else C1.
// MODE 1: fp32 row-major [M][1024] -> C0.
template <int MODE>
__global__ __launch_bounds__(512, 2) void gemm256(
    const u16* __restrict__ Ain, const u16* __restrict__ Bt,
    void* __restrict__ C0p, void* __restrict__ C1p, float scale0) {
    constexpr int NT = DM / 64;  // 16 K-tiles
    __shared__ __align__(16) u16 As[2 * 256 * 64];
    __shared__ __align__(16) u16 Bs[2 * 128 * 64];

    int bx, by;
    supertile_bxby(gridDim.x, &bx, &by);
    int m0 = bx * 256;
    int n0 = by * 128;

    int tid = threadIdx.x;
    int lane = tid & 63, wave = tid >> 6;       // 0..7
    int quad = lane >> 4, l15 = lane & 15;
    int wm = wave >> 1, wn = wave & 1;          // 4M x 2N wave grid

    int rw = lane >> 3;            // 0..7: row within 8-row staging group
    int gsw = (lane & 7) ^ rw;     // pre-swizzled source 16B-granule (involution)

    f32x4 acc[4][4];
    #pragma unroll
    for (int i = 0; i < 4; i++)
        #pragma unroll
        for (int j = 0; j < 4; j++) acc[i][j] = f32x4{0.f, 0.f, 0.f, 0.f};

    // stage one 256x64 A-tile (4 calls) + 128x64 B-tile (2 calls) into buf
    auto stage = [&](int buf, int kst) {
        const u16* ga = Ain + (size_t)(m0 + wave * 32 + rw) * DM + kst + gsw * 8;
        u16* la = As + buf * (256 * 64) + (wave * 32) * 64;
        #pragma unroll
        for (int c = 0; c < 4; c++)
            gload16_lds(ga + (size_t)(c * 8) * DM, la + c * 8 * 64);
        const u16* gb = Bt + (size_t)(n0 + wave * 16 + rw) * DM + kst + gsw * 8;
        u16* lb = Bs + buf * (128 * 64) + (wave * 16) * 64;
        gload16_lds(gb, lb);
        gload16_lds(gb + (size_t)8 * DM, lb + 8 * 64);
    };

    // prologue: tiles 0 and 1 in flight (12 calls)
    stage(0, 0);
    stage(1, 64);

    int sw = l15 & 7;   // row&7 for fragment reads (row offsets are multiples of 16)
    for (int t = 0; t < NT; ++t) {
        int buf = t & 1;
        // tile t landed (only tile t+1's 6 calls may remain in flight)
        asm volatile("s_waitcnt vmcnt(6)" ::: "memory");
        __builtin_amdgcn_s_barrier();

        u16x8 afr[4][2], bfr[4][2];
        {
            const u16* Ab = As + buf * (256 * 64);
            #pragma unroll
            for (int mt = 0; mt < 4; mt++) {
                const u16* rp = Ab + (wm * 64 + mt * 16 + l15) * 64;
                afr[mt][0] = *(const u16x8*)(rp + ((quad ^ sw) << 3));
                afr[mt][1] = *(const u16x8*)(rp + (((4 + quad) ^ sw) << 3));
            }
            const u16* Bb = Bs + buf * (128 * 64);
            #pragma unroll
            for (int nt = 0; nt < 4; nt++) {
                const u16* rp = Bb + (wn * 64 + nt * 16 + l15) * 64;
                bfr[nt][0] = *(const u16x8*)(rp + ((quad ^ sw) << 3));
                bfr[nt][1] = *(const u16x8*)(rp + (((4 + quad) ^ sw) << 3));
            }
        }
        // all waves' reads of this buf complete -> safe to overwrite
        asm volatile("s_waitcnt lgkmcnt(0)" ::: "memory");
        __builtin_amdgcn_sched_barrier(0);
        __builtin_amdgcn_s_barrier();

        // stage tile t+2 into the freed buf (clamped: tail re-stages never read)
        int t2 = t + 2;
        if (t2 > NT - 1) t2 = NT - 1;
        stage(buf, t2 * 64);

        __builtin_amdgcn_s_setprio(1);
        #pragma unroll
        for (int mt = 0; mt < 4; mt++)
            #pragma unroll
            for (int nt = 0; nt < 4; nt++) {
                acc[mt][nt] = mfma16(afr[mt][0], bfr[nt][0], acc[mt][nt]);
                acc[mt][nt] = mfma16(afr[mt][1], bfr[nt][1], acc[mt][nt]);
            }
        __builtin_amdgcn_s_setprio(0);
    }

    #pragma unroll
    for (int mt = 0; mt < 4; mt++)
        #pragma unroll
        for (int nt = 0; nt < 4; nt++)
            #pragma unroll
            for (int r = 0; r < 4; r++) {
                int m = m0 + wm * 64 + mt * 16 + quad * 4 + r;
                int n = n0 + wn * 64 + nt * 16 + l15;
                float v = acc[mt][nt][r];
                if (MODE == 0) {
                    v *= (n < 1024) ? scale0 : 1.0f;
                    u16* C = (n < 1024) ? (u16*)C0p : (u16*)C1p;
                    int ne = n & 1023;
                    int b = m >> 11, s = m & 2047;
                    int h = ne >> 6, d = ne & 63;
                    C[(((size_t)(b * NH + h) * SEQ) + s) * DK + d] = f2bf(v);
                } else {  // MODE 1
                    ((float*)C0p)[(size_t)m * DM + n] = v;
                }
            }
}

// ---------------- V-GEMM: 128x128x32, fp32 A, LDS-transpose epilogue (R5-verified) --
// Reads fp32 x directly; writes Vt[bh][d][s] via wave-private LDS transpose
// (coalesced dwordx4 stores). Now with supertile scheduling (fp32 A panel 512 KB:
// 4x512KB + 8x256KB = 4 MB supertile).
__global__ __launch_bounds__(256, 2) void gemm_v(
    const float* __restrict__ Ain, const u16* __restrict__ Bt,
    u16* __restrict__ C0p) {
    __shared__ u16 As[128][32];
    __shared__ u16 Bs[128][32];
    const int K = DM;
    int bx, by;
    supertile_bxby(gridDim.x, &bx, &by);
    int m0 = bx * 128;
    int n0 = by * 128;
    int tid = threadIdx.x;
    int lane = tid & 63, wave = tid >> 6;
    int quad = lane >> 4, l15 = lane & 15;
    int wm = wave >> 1, wn = wave & 1;

    f32x4 acc[4][4];
    for (int i = 0; i < 4; i++)
        for (int j = 0; j < 4; j++) acc[i][j] = f32x4{0.f, 0.f, 0.f, 0.f};

    int rS = lane >> 2;
    int cS = (lane & 3) * 8;

    for (int k0 = 0; k0 < K; k0 += 32) {
        __syncthreads();
        for (int i = 0; i < 4; i++) {
            int idx = tid + i * 256;
            int r = idx >> 3, c = (idx & 7) * 4;
            float4 v = *(const float4*)(&Ain[(size_t)(m0 + r) * K + k0 + c]);
            ushort4 o;
            o.x = f2bf(v.x); o.y = f2bf(v.y); o.z = f2bf(v.z); o.w = f2bf(v.w);
            *(ushort4*)(&As[r][c]) = o;
        }
        {
            const u16* gb = &Bt[(size_t)(n0 + wave * 32 + rS) * K + k0 + cS];
            gload16_lds(gb, &Bs[wave * 32][0]);
            gload16_lds(gb + (size_t)16 * K, &Bs[wave * 32 + 16][0]);
        }
        __syncthreads();
        u16x8 af[4], bfv[4];
        for (int mt = 0; mt < 4; mt++)
            af[mt] = *(const u16x8*)(&As[wm * 64 + mt * 16 + l15][quad * 8]);
        for (int nt = 0; nt < 4; nt++)
            bfv[nt] = *(const u16x8*)(&Bs[wn * 64 + nt * 16 + l15][quad * 8]);
        for (int mt = 0; mt < 4; mt++)
            for (int nt = 0; nt < 4; nt++)
                acc[mt][nt] = mfma16(af[mt], bfv[nt], acc[mt][nt]);
    }

    // wave-private transpose epilogue -> coalesced stores to Vt[bh][d][s]
    __shared__ u16 Ct[4][64][68];
    #pragma unroll
    for (int mt = 0; mt < 4; mt++)
        #pragma unroll
        for (int nt = 0; nt < 4; nt++)
            #pragma unroll
            for (int r = 0; r < 4; r++) {
                int mp = mt * 16 + quad * 4 + r;   // s within wave tile
                int np = nt * 16 + l15;            // d within wave tile
                Ct[wave][np][mp] = f2bf(acc[mt][nt][r]);
            }
    __syncthreads();
    int bb = m0 >> 11;
    int hh = (n0 + wn * 64) >> 6;                  // one head per wave
    int s_base = (m0 & 2047) + wm * 64;
    #pragma unroll
    for (int c = 0; c < 8; c++) {
        int np = (lane >> 3) + c * 8;              // d row
        int mp = (lane & 7) * 8;                   // 8 consecutive s
        ushort4 lo = *(const ushort4*)(&Ct[wave][np][mp]);
        ushort4 hi = *(const ushort4*)(&Ct[wave][np][mp + 4]);
        u16x8 v;
        v[0] = lo.x; v[1] = lo.y; v[2] = lo.z; v[3] = lo.w;
        v[4] = hi.x; v[5] = hi.y; v[6] = hi.z; v[7] = hi.w;
        size_t addr = ((size_t)(bb * NH + hh) * DK + np) * SEQ + s_base + mp;
        *(u16x8*)(&C0p[addr]) = v;
    }
}

// ---------------- causal flash attention v7 (do not touch; ~73-81 us) ----------------
// Q pre-scaled by (1/8)*log2(e). K: [bh][s][64]. Vt: [bh][d][s]. Out: [b*SEQ+s][h*64+d] bf16.
// Grid (bh, 16): qs = 15 - blockIdx.y (longest-first); XCD = bh%8 preserved.
// Block = 4 waves x 32 q-rows = 128 q-rows; KV tile 64 keys, double-buffered+swizzled.
// Two independent q-group chains per wave per iteration; 16-MFMA setprio clusters (T5).
// P scratch [4][32][64] XOR-swizzled, stored with f2bf_trunc (P in [0,1]).
// LDS 48 KB -> 3 blocks/CU. Waves 0-1 skip the final (fully-masked) key tile.
__global__ __launch_bounds__(256, 3) void attn_kernel(
    const u16* __restrict__ Qb, const u16* __restrict__ Kb,
    const u16* __restrict__ Vtb, u16* __restrict__ AOb) {
    __shared__ u16 Kl[2][64][64];   // [buf][key][d], swizzled 16B granules
    __shared__ u16 Vl[2][64][64];   // [buf][d][key], swizzled 16B granules
    __shared__ u16 Pl[4][32][64];   // [wave][qrow][key], swizzled 16B granules

    int bh = blockIdx.x;            // 0..63
    int qs = 15 - blockIdx.y;       // longest blocks first
    int q0 = qs * 128;
    int tid = threadIdx.x, lane = tid & 63, wave = tid >> 6;  // wave 0..3
    int quad = lane >> 4, l15 = lane & 15;
    int b = bh >> 4, h = bh & 15;

    const u16* Qg = Qb + (size_t)bh * SEQ * DK;
    const u16* Kg = Kb + (size_t)bh * SEQ * DK;
    const u16* Vg = Vtb + (size_t)bh * DK * SEQ;

    int rw = lane >> 3;             // 0..7: row-within-8 for staging
    int gsw = (lane & 7) ^ rw;      // pre-swizzled source 16B-granule
    int sw8 = l15 & 7;              // row&7 for fragment reads
    u16* Pw = &Pl[wave][0][0];

    // Q fragments: global -> regs; wave owns q rows [32w, 32w+32), 2 groups of 16
    u16x8 aq[2][2];
    for (int g = 0; g < 2; g++)
        for (int kc = 0; kc < 2; kc++)
            aq[g][kc] = *(const u16x8*)(
                &Qg[(size_t)(q0 + wave * 32 + g * 16 + l15) * DK + kc * 32 + quad * 8]);

    float lsum[2][4];
    f32x4 O[2][4];
    for (int g = 0; g < 2; g++)
        for (int r = 0; r < 4; r++) lsum[g][r] = 0.f;
    for (int g = 0; g < 2; g++)
        for (int nt = 0; nt < 4; nt++) O[g][nt] = f32x4{0.f, 0.f, 0.f, 0.f};

    // prologue: stage tile 0 into buf 0
    {
        const u16* gk = &Kg[(size_t)(wave * 16 + rw) * DK + gsw * 8];
        gload16_lds(gk, &Kl[0][wave * 16][0]);
        gload16_lds(gk + 8 * DK, &Kl[0][wave * 16 + 8][0]);
        const u16* gv = &Vg[(size_t)(wave * 16 + rw) * SEQ + gsw * 8];
        gload16_lds(gv, &Vl[0][wave * 16][0]);
        gload16_lds(gv + 8 * SEQ, &Vl[0][wave * 16 + 8][0]);
    }
    __syncthreads();

    int nkt = 2 * qs + 2;                 // key tiles for this q block
    int lastkt = 2 * qs + (wave >> 1);    // this wave's diagonal tile
    int buf = 0;
    for (int kt = 0; kt < nkt; kt++) {
        // issue next tile's loads into buf^1; in flight across compute
        if (kt + 1 < nkt) {
            int k0n = (kt + 1) * 64;
            const u16* gk = &Kg[(size_t)(k0n + wave * 16 + rw) * DK + gsw * 8];
            gload16_lds(gk, &Kl[buf ^ 1][wave * 16][0]);
            gload16_lds(gk + 8 * DK, &Kl[buf ^ 1][wave * 16 + 8][0]);
            const u16* gv = &Vg[(size_t)(wave * 16 + rw) * SEQ + k0n + gsw * 8];
            gload16_lds(gv, &Vl[buf ^ 1][wave * 16][0]);
            gload16_lds(gv + 8 * SEQ, &Vl[buf ^ 1][wave * 16 + 8][0]);
        }

        if (kt <= lastkt) {   // wave-uniform; waves 0-1 skip their fully-masked last tile
            bool diag = (kt == lastkt);
            // S = Q K^T : 16 MFMA (two 16x64 tiles), swizzled conflict-free reads
            f32x4 sc[2][4];
            __builtin_amdgcn_s_setprio(1);
            #pragma unroll
            for (int nt = 0; nt < 4; nt++) {
                const u16* kr = &Kl[buf][nt * 16 + l15][0];
                u16x8 b0 = *(const u16x8*)(kr + (quad ^ sw8) * 8);
                u16x8 b1 = *(const u16x8*)(kr + ((4 + quad) ^ sw8) * 8);
                #pragma unroll
                for (int g = 0; g < 2; g++) {
                    f32x4 z = f32x4{0.f, 0.f, 0.f, 0.f};
                    z = mfma16(aq[g][0], b0, z);
                    z = mfma16(aq[g][1], b1, z);
                    sc[g][nt] = z;
                }
            }
            __builtin_amdgcn_s_setprio(0);
            // P = exp2(S); causal mask only on the wave's diagonal tile
            #pragma unroll
            for (int g = 0; g < 2; g++) {
                if (diag) {
                    #pragma unroll
                    for (int nt = 0; nt < 4; nt++)
                        #pragma unroll
                        for (int r = 0; r < 4; r++) {
                            int qq = q0 + wave * 32 + g * 16 + quad * 4 + r;
                            int kk = kt * 64 + nt * 16 + l15;
                            float e = exp2f(sc[g][nt][r]);
                            float pv = (kk <= qq) ? e : 0.f;
                            sc[g][nt][r] = pv;
                            lsum[g][r] += pv;
                        }
                } else {
                    #pragma unroll
                    for (int nt = 0; nt < 4; nt++)
                        #pragma unroll
                        for (int r = 0; r < 4; r++) {
                            float pv = exp2f(sc[g][nt][r]);
                            sc[g][nt][r] = pv;
                            lsum[g][r] += pv;
                        }
                }
                // P -> wave-private swizzled LDS slice; truncating cvt
                #pragma unroll
                for (int nt = 0; nt < 4; nt++)
                    #pragma unroll
                    for (int r = 0; r < 4; r++) {
                        int prow = g * 16 + quad * 4 + r;
                        int pcol = nt * 16 + l15;
                        int scol = (((pcol >> 3) ^ (prow & 7)) << 3) | (pcol & 7);
                        Pw[prow * 64 + scol] = f2bf_trunc(sc[g][nt][r]);
                    }
            }
            // O += P V : 16 MFMA
            u16x8 ap[2][2];
            #pragma unroll
            for (int g = 0; g < 2; g++)
                #pragma unroll
                for (int kc = 0; kc < 2; kc++)
                    ap[g][kc] = *(const u16x8*)(
                        &Pw[(g * 16 + l15) * 64 + (((kc * 4 + quad) ^ sw8) << 3)]);
            __builtin_amdgcn_s_setprio(1);
            #pragma unroll
            for (int nt = 0; nt < 4; nt++) {
                const u16* vr = &Vl[buf][nt * 16 + l15][0];
                u16x8 b0 = *(const u16x8*)(vr + (quad ^ sw8) * 8);
                u16x8 b1 = *(const u16x8*)(vr + ((4 + quad) ^ sw8) * 8);
                #pragma unroll
                for (int g = 0; g < 2; g++) {
                    O[g][nt] = mfma16(ap[g][0], b0, O[g][nt]);
                    O[g][nt] = mfma16(ap[g][1], b1, O[g][nt]);
                }
            }
            __builtin_amdgcn_s_setprio(0);
        }
        __syncthreads();  // drains vmcnt (next tile staged) + all buf reads done
        buf ^= 1;
    }

    // epilogue: reduce lsum across the 16 column lanes, normalize, store
    #pragma unroll
    for (int g = 0; g < 2; g++)
        #pragma unroll
        for (int r = 0; r < 4; r++) {
            float s = lsum[g][r];
            for (int off = 1; off < 16; off <<= 1) s += __shfl_xor(s, off, 64);
            float inv = 1.0f / s;
            int q = q0 + wave * 32 + g * 16 + quad * 4 + r;
            #pragma unroll
            for (int nt = 0; nt < 4; nt++) {
                int d = nt * 16 + l15;
                AOb[((size_t)(b * SEQ + q)) * DM + h * DK + d] = f2bf(O[g][nt][r] * inv);
            }
        }
}

extern "C" void kernel_launch(void* const* d_in, const int* in_sizes, int n_in,
                              void* d_out, int out_size, void* d_ws, size_t ws_size,
                              hipStream_t stream) {
    const float* x = (const float*)d_in[0];
    const float* Wq = (const float*)d_in[1];
    const float* Wk = (const float*)d_in[2];
    const float* Wv = (const float*)d_in[3];
    const float* Wo = (const float*)d_in[4];
    float* out = (float*)d_out;

    // Regions: ws = S0|S1 (16 MB each), d_out = D0|D1 (16 MB each).
    // 1. cvt x -> xb@S0
    // 2. T(Wq,Wk) -> wqk@D0 head (4 MB)
    // 3. gemm256<0>(xb, wqk) -> Q@S1 (scaled), K@D1
    // 4. T(Wv) -> wvt@S0 head (xb dead: V-GEMM reads fp32 x directly)
    // 5. gemm_v(x fp32, wvt) -> Vt@D0 [bh][d][s] (overwrites wqk head)
    // 6. attn(Q@S1, K@D1, Vt@D0) -> AO@S0 (over dead wvt/xb)
    // 7. T(Wo) -> wot@S1 head (Q dead)
    // 8. gemm256<1>(AO@S0, wot@S1h) -> d_out fp32 (D0+D1; Vt,K dead)
    const size_t HALF = (size_t)M_TOT * DM * 2;  // 16 MB
    char* S0 = (char*)d_ws;
    char* S1 = (char*)d_ws + HALF;
    char* D0 = (char*)d_out;
    char* D1 = (char*)d_out + HALF;

    u16* xb  = (u16*)S0;
    u16* Qb  = (u16*)S1;
    u16* Kb  = (u16*)D1;
    u16* Vt  = (u16*)D0;
    u16* AOb = (u16*)S0;
    u16* wqk = (u16*)D0;   // 4 MB
    u16* wvt = (u16*)S0;   // 2 MB over dead xb
    u16* wot = (u16*)S1;   // 2 MB over dead Q

    const float cscale = 0.125f * 1.44269504088896f;  // 1/sqrt(64) * log2(e)
    dim3 tg2(32, 32, 2);
    dim3 tg1(32, 32, 1);

    // 1) x -> bf16
    int n4 = M_TOT * DM / 4;
    cvt_bf16_kernel<<<n4 / 256, 256, 0, stream>>>(x, xb, n4);

    // 2-3) fused Q,K projection (Q pre-scaled), 256x128 tiles
    transpose_w_kernel<<<tg2, 256, 0, stream>>>(Wq, Wk, wqk);
    dim3 gqk(M_TOT / 256, 2048 / 128);   // 32 x 16 = 512 blocks
    gemm256<0><<<gqk, 512, 0, stream>>>(xb, wqk, (void*)Qb, (void*)Kb, cscale);

    // 4-5) V projection with fused transpose (fp32 A from d_in)
    transpose_w_kernel<<<tg1, 256, 0, stream>>>(Wv, Wv, wvt);
    dim3 gv(M_TOT / 128, DM / 128);      // 64 x 8
    gemm_v<<<gv, 256, 0, stream>>>(x, wvt, Vt);

    // 6) attention
    dim3 ag(BH, 16);
    attn_kernel<<<ag, 256, 0, stream>>>(Qb, Kb, Vt, AOb);

    // 7-8) output projection straight into d_out, 256x128 tiles
    transpose_w_kernel<<<tg1, 256, 0, stream>>>(Wo, Wo, wot);
    dim3 go(M_TOT / 256, DM / 128);      // 32 x 8 = 256 blocks
    gemm256<1><<<go, 512, 0, stream>>>(AOb, wot, (void*)out, (void*)out, 1.0f);
}

// Round 9
// 257.694 us; speedup vs baseline: 1.0782x; 1.0278x over previous
//
#include <hip/hip_runtime.h>
#include <hip/hip_bf16.h>
#include <stdint.h>

#define B_SZ 4
#define SEQ 2048
#define DM 1024
#define NH 16
#define DK 64
#define BH (B_SZ * NH)      // 64
#define M_TOT (B_SZ * SEQ)  // 8192

typedef unsigned short u16;
typedef u16 u16x8 __attribute__((ext_vector_type(8)));
typedef __bf16 bf16x8 __attribute__((ext_vector_type(8)));
typedef float f32x4 __attribute__((ext_vector_type(4)));

// native RNE fp32->bf16 (single v_cvt instr on gfx950)
__device__ __forceinline__ u16 f2bf(float f) {
    return __builtin_bit_cast(u16, (__bf16)f);
}

// truncating fp32->bf16 (1 shift; used only for P in [0,1] -- v7-verified)
__device__ __forceinline__ u16 f2bf_trunc(float f) {
    union { float f; uint32_t u; } v; v.f = f;
    return (u16)(v.u >> 16);
}

__device__ __forceinline__ f32x4 mfma16(u16x8 a, u16x8 b, f32x4 c) {
    return __builtin_amdgcn_mfma_f32_16x16x32_bf16(
        __builtin_bit_cast(bf16x8, a), __builtin_bit_cast(bf16x8, b), c, 0, 0, 0);
}

// async global->LDS, 16 B per lane; lds dest = wave-uniform base + lane*16
__device__ __forceinline__ void gload16_lds(const void* g, void* l) {
    __builtin_amdgcn_global_load_lds(
        (const __attribute__((address_space(1))) void*)(uintptr_t)g,
        (__attribute__((address_space(3))) void*)(uintptr_t)l, 16, 0, 0);
}

// ---------------- x fp32 -> bf16 ----------------
__global__ void cvt_bf16_kernel(const float* __restrict__ in, u16* __restrict__ out, int n4) {
    int i = blockIdx.x * blockDim.x + threadIdx.x;
    if (i < n4) {
        float4 v = ((const float4*)in)[i];
        ushort4 o;
        o.x = f2bf(v.x); o.y = f2bf(v.y); o.z = f2bf(v.z); o.w = f2bf(v.w);
        ((ushort4*)out)[i] = o;
    }
}

// ---------------- W [K][N] fp32 -> Wt [N][K] bf16 (z = weight index) ----------------
__global__ void transpose_w_kernel(const float* __restrict__ W0, const float* __restrict__ W1,
                                   u16* __restrict__ Wt) {
    __shared__ u16 tile[32][33];
    int bx = blockIdx.x, by = blockIdx.y, z = blockIdx.z;
    const float* W = z ? W1 : W0;
    u16* Wd = Wt + (size_t)z * DM * DM;
    int t = threadIdx.x;
    for (int i = 0; i < 4; i++) {
        int idx = t + i * 256;
        int r = idx >> 5, c = idx & 31;
        tile[r][c] = f2bf(W[(by * 32 + r) * DM + bx * 32 + c]);
    }
    __syncthreads();
    for (int i = 0; i < 4; i++) {
        int idx = t + i * 256;
        int r2 = idx >> 5, c2 = idx & 31;
        Wd[(bx * 32 + r2) * DM + by * 32 + c2] = tile[c2][r2];
    }
}

// L2-supertile XCD scheduling (pure bijective block reorder; no numeric effect).
__device__ __forceinline__ void supertile_bxby(int gm, int* bxp, int* byp) {
    int wg = blockIdx.x + blockIdx.y * gm;
    int j = (wg >> 3) & 31;                 // slot within supertile
    int s = (wg & 7) + ((wg >> 8) << 3);    // supertile id = xcd + 8*round
    int sxc = gm >> 2;                      // supertiles along m
    *bxp = (s % sxc) * 4 + (j & 3);
    *byp = (s / sxc) * 8 + (j >> 2);
}

// ---------------- 256x128 bf16 GEMM, BK=64, triple-buffer-A single-barrier ----------
// v9: A triple-buffered (stage t+2), B double-buffered (stage t+1) -> the staged
// buffer is never the read buffer -> NO mid-iteration WAR barrier/lgkm drain.
// Per K-tile: vmcnt(4) [A(t),B(t) landed; only A(t+1) in flight] -> s_barrier ->
// stage B(t+1)+A(t+2) (issued FIRST: full-iteration latency cover) -> 16 swizzled
// ds_read_b128 (compiler fine-lgkmcnt) -> setprio + 32 MFMA. ONE barrier/K-tile.
// Hazards: RAW by vmcnt(4)+barrier (queue order A(t),B(t),A(t+1)); WAR safe since
// stage targets were last read at iter t-1, and reads are consumed by that wave's
// MFMAs before it passes the iter-t barrier. Clamped tail stages target disjoint
// buffers (never read). LDS 3x32+2x16 = 128 KB -> 1 block/CU, 8 waves.
// MODE 0: bf16 scatter to [bh][s][dk]; n<1024 -> C0 (scaled by scale0), else C1.
// MODE 1: fp32 row-major [M][1024] -> C0.
template <int MODE>
__global__ __launch_bounds__(512, 2) void gemm256(
    const u16* __restrict__ Ain, const u16* __restrict__ Bt,
    void* __restrict__ C0p, void* __restrict__ C1p, float scale0) {
    constexpr int NT = DM / 64;  // 16 K-tiles
    __shared__ __align__(16) u16 As[3 * 256 * 64];   // 96 KB, 3 buffers
    __shared__ __align__(16) u16 Bs[2 * 128 * 64];   // 32 KB, 2 buffers

    int bx, by;
    supertile_bxby(gridDim.x, &bx, &by);
    int m0 = bx * 256;
    int n0 = by * 128;

    int tid = threadIdx.x;
    int lane = tid & 63, wave = tid >> 6;       // 0..7
    int quad = lane >> 4, l15 = lane & 15;
    int wm = wave >> 1, wn = wave & 1;          // 4M x 2N wave grid

    int rw = lane >> 3;            // 0..7: row within 8-row staging group
    int gsw = (lane & 7) ^ rw;     // pre-swizzled source 16B-granule (involution)

    f32x4 acc[4][4];
    #pragma unroll
    for (int i = 0; i < 4; i++)
        #pragma unroll
        for (int j = 0; j < 4; j++) acc[i][j] = f32x4{0.f, 0.f, 0.f, 0.f};

    // stage one 256x64 A-tile (4 calls/thread) into A-buf
    auto stageA = [&](int buf, int kst) {
        const u16* ga = Ain + (size_t)(m0 + wave * 32 + rw) * DM + kst + gsw * 8;
        u16* la = As + buf * (256 * 64) + (wave * 32) * 64;
        #pragma unroll
        for (int c = 0; c < 4; c++)
            gload16_lds(ga + (size_t)(c * 8) * DM, la + c * 8 * 64);
    };
    // stage one 128x64 B-tile (2 calls/thread) into B-buf
    auto stageB = [&](int buf, int kst) {
        const u16* gb = Bt + (size_t)(n0 + wave * 16 + rw) * DM + kst + gsw * 8;
        u16* lb = Bs + buf * (128 * 64) + (wave * 16) * 64;
        gload16_lds(gb, lb);
        gload16_lds(gb + (size_t)8 * DM, lb + 8 * 64);
    };

    // prologue: B(0), A(0), A(1) in flight (10 loads; oldest 6 = B0+A0)
    stageB(0, 0);
    stageA(0, 0);
    stageA(1, 64);

    int sw = l15 & 7;   // row&7 for fragment reads (row offsets are multiples of 16)
    for (int t = 0; t < NT; ++t) {
        // A(t)+B(t) landed (oldest 6 of [A(t)4,B(t)2,A(t+1)4]); A(t+1) may remain
        asm volatile("s_waitcnt vmcnt(4)" ::: "memory");
        __builtin_amdgcn_s_barrier();

        // stage next tiles FIRST (full-iteration latency cover). B before A so
        // vmcnt ordering at the next iteration drains B(t+1) with A(t+1).
        int tb = t + 1; if (tb > NT - 1) tb = NT - 1;
        int ta = t + 2; if (ta > NT - 1) ta = NT - 1;
        stageB((t + 1) & 1, tb * 64);
        stageA((t + 2) % 3, ta * 64);

        // fragment reads (swizzled, conflict-free); compiler emits fine lgkmcnt
        u16x8 afr[4][2], bfr[4][2];
        {
            const u16* Ab = As + (t % 3) * (256 * 64);
            #pragma unroll
            for (int mt = 0; mt < 4; mt++) {
                const u16* rp = Ab + (wm * 64 + mt * 16 + l15) * 64;
                afr[mt][0] = *(const u16x8*)(rp + ((quad ^ sw) << 3));
                afr[mt][1] = *(const u16x8*)(rp + (((4 + quad) ^ sw) << 3));
            }
            const u16* Bb = Bs + (t & 1) * (128 * 64);
            #pragma unroll
            for (int nt = 0; nt < 4; nt++) {
                const u16* rp = Bb + (wn * 64 + nt * 16 + l15) * 64;
                bfr[nt][0] = *(const u16x8*)(rp + ((quad ^ sw) << 3));
                bfr[nt][1] = *(const u16x8*)(rp + (((4 + quad) ^ sw) << 3));
            }
        }

        __builtin_amdgcn_s_setprio(1);
        #pragma unroll
        for (int mt = 0; mt < 4; mt++)
            #pragma unroll
            for (int nt = 0; nt < 4; nt++) {
                acc[mt][nt] = mfma16(afr[mt][0], bfr[nt][0], acc[mt][nt]);
                acc[mt][nt] = mfma16(afr[mt][1], bfr[nt][1], acc[mt][nt]);
            }
        __builtin_amdgcn_s_setprio(0);
    }

    #pragma unroll
    for (int mt = 0; mt < 4; mt++)
        #pragma unroll
        for (int nt = 0; nt < 4; nt++)
            #pragma unroll
            for (int r = 0; r < 4; r++) {
                int m = m0 + wm * 64 + mt * 16 + quad * 4 + r;
                int n = n0 + wn * 64 + nt * 16 + l15;
                float v = acc[mt][nt][r];
                if (MODE == 0) {
                    v *= (n < 1024) ? scale0 : 1.0f;
                    u16* C = (n < 1024) ? (u16*)C0p : (u16*)C1p;
                    int ne = n & 1023;
                    int b = m >> 11, s = m & 2047;
                    int h = ne >> 6, d = ne & 63;
                    C[(((size_t)(b * NH + h) * SEQ) + s) * DK + d] = f2bf(v);
                } else {  // MODE 1
                    ((float*)C0p)[(size_t)m * DM + n] = v;
                }
            }
}

// ---------------- V-GEMM: 128x128x32, fp32 A, LDS-transpose epilogue (R5-verified) --
// Reads fp32 x directly; writes Vt[bh][d][s] via wave-private LDS transpose
// (coalesced dwordx4 stores). Supertile scheduling.
__global__ __launch_bounds__(256, 2) void gemm_v(
    const float* __restrict__ Ain, const u16* __restrict__ Bt,
    u16* __restrict__ C0p) {
    __shared__ u16 As[128][32];
    __shared__ u16 Bs[128][32];
    const int K = DM;
    int bx, by;
    supertile_bxby(gridDim.x, &bx, &by);
    int m0 = bx * 128;
    int n0 = by * 128;
    int tid = threadIdx.x;
    int lane = tid & 63, wave = tid >> 6;
    int quad = lane >> 4, l15 = lane & 15;
    int wm = wave >> 1, wn = wave & 1;

    f32x4 acc[4][4];
    for (int i = 0; i < 4; i++)
        for (int j = 0; j < 4; j++) acc[i][j] = f32x4{0.f, 0.f, 0.f, 0.f};

    int rS = lane >> 2;
    int cS = (lane & 3) * 8;

    for (int k0 = 0; k0 < K; k0 += 32) {
        __syncthreads();
        for (int i = 0; i < 4; i++) {
            int idx = tid + i * 256;
            int r = idx >> 3, c = (idx & 7) * 4;
            float4 v = *(const float4*)(&Ain[(size_t)(m0 + r) * K + k0 + c]);
            ushort4 o;
            o.x = f2bf(v.x); o.y = f2bf(v.y); o.z = f2bf(v.z); o.w = f2bf(v.w);
            *(ushort4*)(&As[r][c]) = o;
        }
        {
            const u16* gb = &Bt[(size_t)(n0 + wave * 32 + rS) * K + k0 + cS];
            gload16_lds(gb, &Bs[wave * 32][0]);
            gload16_lds(gb + (size_t)16 * K, &Bs[wave * 32 + 16][0]);
        }
        __syncthreads();
        u16x8 af[4], bfv[4];
        for (int mt = 0; mt < 4; mt++)
            af[mt] = *(const u16x8*)(&As[wm * 64 + mt * 16 + l15][quad * 8]);
        for (int nt = 0; nt < 4; nt++)
            bfv[nt] = *(const u16x8*)(&Bs[wn * 64 + nt * 16 + l15][quad * 8]);
        for (int mt = 0; mt < 4; mt++)
            for (int nt = 0; nt < 4; nt++)
                acc[mt][nt] = mfma16(af[mt], bfv[nt], acc[mt][nt]);
    }

    // wave-private transpose epilogue -> coalesced stores to Vt[bh][d][s]
    __shared__ u16 Ct[4][64][68];
    #pragma unroll
    for (int mt = 0; mt < 4; mt++)
        #pragma unroll
        for (int nt = 0; nt < 4; nt++)
            #pragma unroll
            for (int r = 0; r < 4; r++) {
                int mp = mt * 16 + quad * 4 + r;   // s within wave tile
                int np = nt * 16 + l15;            // d within wave tile
                Ct[wave][np][mp] = f2bf(acc[mt][nt][r]);
            }
    __syncthreads();
    int bb = m0 >> 11;
    int hh = (n0 + wn * 64) >> 6;                  // one head per wave
    int s_base = (m0 & 2047) + wm * 64;
    #pragma unroll
    for (int c = 0; c < 8; c++) {
        int np = (lane >> 3) + c * 8;              // d row
        int mp = (lane & 7) * 8;                   // 8 consecutive s
        ushort4 lo = *(const ushort4*)(&Ct[wave][np][mp]);
        ushort4 hi = *(const ushort4*)(&Ct[wave][np][mp + 4]);
        u16x8 v;
        v[0] = lo.x; v[1] = lo.y; v[2] = lo.z; v[3] = lo.w;
        v[4] = hi.x; v[5] = hi.y; v[6] = hi.z; v[7] = hi.w;
        size_t addr = ((size_t)(bb * NH + hh) * DK + np) * SEQ + s_base + mp;
        *(u16x8*)(&C0p[addr]) = v;
    }
}

// ---------------- causal flash attention v7 (do not touch; ~73-81 us) ----------------
// Q pre-scaled by (1/8)*log2(e). K: [bh][s][64]. Vt: [bh][d][s]. Out: [b*SEQ+s][h*64+d] bf16.
// Grid (bh, 16): qs = 15 - blockIdx.y (longest-first); XCD = bh%8 preserved.
// Block = 4 waves x 32 q-rows = 128 q-rows; KV tile 64 keys, double-buffered+swizzled.
// Two independent q-group chains per wave per iteration; 16-MFMA setprio clusters (T5).
// P scratch [4][32][64] XOR-swizzled, stored with f2bf_trunc (P in [0,1]).
// LDS 48 KB -> 3 blocks/CU. Waves 0-1 skip the final (fully-masked) key tile.
__global__ __launch_bounds__(256, 3) void attn_kernel(
    const u16* __restrict__ Qb, const u16* __restrict__ Kb,
    const u16* __restrict__ Vtb, u16* __restrict__ AOb) {
    __shared__ u16 Kl[2][64][64];   // [buf][key][d], swizzled 16B granules
    __shared__ u16 Vl[2][64][64];   // [buf][d][key], swizzled 16B granules
    __shared__ u16 Pl[4][32][64];   // [wave][qrow][key], swizzled 16B granules

    int bh = blockIdx.x;            // 0..63
    int qs = 15 - blockIdx.y;       // longest blocks first
    int q0 = qs * 128;
    int tid = threadIdx.x, lane = tid & 63, wave = tid >> 6;  // wave 0..3
    int quad = lane >> 4, l15 = lane & 15;
    int b = bh >> 4, h = bh & 15;

    const u16* Qg = Qb + (size_t)bh * SEQ * DK;
    const u16* Kg = Kb + (size_t)bh * SEQ * DK;
    const u16* Vg = Vtb + (size_t)bh * DK * SEQ;

    int rw = lane >> 3;             // 0..7: row-within-8 for staging
    int gsw = (lane & 7) ^ rw;      // pre-swizzled source 16B-granule
    int sw8 = l15 & 7;              // row&7 for fragment reads
    u16* Pw = &Pl[wave][0][0];

    // Q fragments: global -> regs; wave owns q rows [32w, 32w+32), 2 groups of 16
    u16x8 aq[2][2];
    for (int g = 0; g < 2; g++)
        for (int kc = 0; kc < 2; kc++)
            aq[g][kc] = *(const u16x8*)(
                &Qg[(size_t)(q0 + wave * 32 + g * 16 + l15) * DK + kc * 32 + quad * 8]);

    float lsum[2][4];
    f32x4 O[2][4];
    for (int g = 0; g < 2; g++)
        for (int r = 0; r < 4; r++) lsum[g][r] = 0.f;
    for (int g = 0; g < 2; g++)
        for (int nt = 0; nt < 4; nt++) O[g][nt] = f32x4{0.f, 0.f, 0.f, 0.f};

    // prologue: stage tile 0 into buf 0
    {
        const u16* gk = &Kg[(size_t)(wave * 16 + rw) * DK + gsw * 8];
        gload16_lds(gk, &Kl[0][wave * 16][0]);
        gload16_lds(gk + 8 * DK, &Kl[0][wave * 16 + 8][0]);
        const u16* gv = &Vg[(size_t)(wave * 16 + rw) * SEQ + gsw * 8];
        gload16_lds(gv, &Vl[0][wave * 16][0]);
        gload16_lds(gv + 8 * SEQ, &Vl[0][wave * 16 + 8][0]);
    }
    __syncthreads();

    int nkt = 2 * qs + 2;                 // key tiles for this q block
    int lastkt = 2 * qs + (wave >> 1);    // this wave's diagonal tile
    int buf = 0;
    for (int kt = 0; kt < nkt; kt++) {
        // issue next tile's loads into buf^1; in flight across compute
        if (kt + 1 < nkt) {
            int k0n = (kt + 1) * 64;
            const u16* gk = &Kg[(size_t)(k0n + wave * 16 + rw) * DK + gsw * 8];
            gload16_lds(gk, &Kl[buf ^ 1][wave * 16][0]);
            gload16_lds(gk + 8 * DK, &Kl[buf ^ 1][wave * 16 + 8][0]);
            const u16* gv = &Vg[(size_t)(wave * 16 + rw) * SEQ + k0n + gsw * 8];
            gload16_lds(gv, &Vl[buf ^ 1][wave * 16][0]);
            gload16_lds(gv + 8 * SEQ, &Vl[buf ^ 1][wave * 16 + 8][0]);
        }

        if (kt <= lastkt) {   // wave-uniform; waves 0-1 skip their fully-masked last tile
            bool diag = (kt == lastkt);
            // S = Q K^T : 16 MFMA (two 16x64 tiles), swizzled conflict-free reads
            f32x4 sc[2][4];
            __builtin_amdgcn_s_setprio(1);
            #pragma unroll
            for (int nt = 0; nt < 4; nt++) {
                const u16* kr = &Kl[buf][nt * 16 + l15][0];
                u16x8 b0 = *(const u16x8*)(kr + (quad ^ sw8) * 8);
                u16x8 b1 = *(const u16x8*)(kr + ((4 + quad) ^ sw8) * 8);
                #pragma unroll
                for (int g = 0; g < 2; g++) {
                    f32x4 z = f32x4{0.f, 0.f, 0.f, 0.f};
                    z = mfma16(aq[g][0], b0, z);
                    z = mfma16(aq[g][1], b1, z);
                    sc[g][nt] = z;
                }
            }
            __builtin_amdgcn_s_setprio(0);
            // P = exp2(S); causal mask only on the wave's diagonal tile
            #pragma unroll
            for (int g = 0; g < 2; g++) {
                if (diag) {
                    #pragma unroll
                    for (int nt = 0; nt < 4; nt++)
                        #pragma unroll
                        for (int r = 0; r < 4; r++) {
                            int qq = q0 + wave * 32 + g * 16 + quad * 4 + r;
                            int kk = kt * 64 + nt * 16 + l15;
                            float e = exp2f(sc[g][nt][r]);
                            float pv = (kk <= qq) ? e : 0.f;
                            sc[g][nt][r] = pv;
                            lsum[g][r] += pv;
                        }
                } else {
                    #pragma unroll
                    for (int nt = 0; nt < 4; nt++)
                        #pragma unroll
                        for (int r = 0; r < 4; r++) {
                            float pv = exp2f(sc[g][nt][r]);
                            sc[g][nt][r] = pv;
                            lsum[g][r] += pv;
                        }
                }
                // P -> wave-private swizzled LDS slice; truncating cvt
                #pragma unroll
                for (int nt = 0; nt < 4; nt++)
                    #pragma unroll
                    for (int r = 0; r < 4; r++) {
                        int prow = g * 16 + quad * 4 + r;
                        int pcol = nt * 16 + l15;
                        int scol = (((pcol >> 3) ^ (prow & 7)) << 3) | (pcol & 7);
                        Pw[prow * 64 + scol] = f2bf_trunc(sc[g][nt][r]);
                    }
            }
            // O += P V : 16 MFMA
            u16x8 ap[2][2];
            #pragma unroll
            for (int g = 0; g < 2; g++)
                #pragma unroll
                for (int kc = 0; kc < 2; kc++)
                    ap[g][kc] = *(const u16x8*)(
                        &Pw[(g * 16 + l15) * 64 + (((kc * 4 + quad) ^ sw8) << 3)]);
            __builtin_amdgcn_s_setprio(1);
            #pragma unroll
            for (int nt = 0; nt < 4; nt++) {
                const u16* vr = &Vl[buf][nt * 16 + l15][0];
                u16x8 b0 = *(const u16x8*)(vr + (quad ^ sw8) * 8);
                u16x8 b1 = *(const u16x8*)(vr + ((4 + quad) ^ sw8) * 8);
                #pragma unroll
                for (int g = 0; g < 2; g++) {
                    O[g][nt] = mfma16(ap[g][0], b0, O[g][nt]);
                    O[g][nt] = mfma16(ap[g][1], b1, O[g][nt]);
                }
            }
            __builtin_amdgcn_s_setprio(0);
        }
        __syncthreads();  // drains vmcnt (next tile staged) + all buf reads done
        buf ^= 1;
    }

    // epilogue: reduce lsum across the 16 column lanes, normalize, store
    #pragma unroll
    for (int g = 0; g < 2; g++)
        #pragma unroll
        for (int r = 0; r < 4; r++) {
            float s = lsum[g][r];
            for (int off = 1; off < 16; off <<= 1) s += __shfl_xor(s, off, 64);
            float inv = 1.0f / s;
            int q = q0 + wave * 32 + g * 16 + quad * 4 + r;
            #pragma unroll
            for (int nt = 0; nt < 4; nt++) {
                int d = nt * 16 + l15;
                AOb[((size_t)(b * SEQ + q)) * DM + h * DK + d] = f2bf(O[g][nt][r] * inv);
            }
        }
}

extern "C" void kernel_launch(void* const* d_in, const int* in_sizes, int n_in,
                              void* d_out, int out_size, void* d_ws, size_t ws_size,
                              hipStream_t stream) {
    const float* x = (const float*)d_in[0];
    const float* Wq = (const float*)d_in[1];
    const float* Wk = (const float*)d_in[2];
    const float* Wv = (const float*)d_in[3];
    const float* Wo = (const float*)d_in[4];
    float* out = (float*)d_out;

    // Regions: ws = S0|S1 (16 MB each), d_out = D0|D1 (16 MB each).
    // 1. cvt x -> xb@S0
    // 2. T(Wq,Wk) -> wqk@D0 head (4 MB)
    // 3. gemm256<0>(xb, wqk) -> Q@S1 (scaled), K@D1
    // 4. T(Wv) -> wvt@S0 head (xb dead: V-GEMM reads fp32 x directly)
    // 5. gemm_v(x fp32, wvt) -> Vt@D0 [bh][d][s] (overwrites wqk head)
    // 6. attn(Q@S1, K@D1, Vt@D0) -> AO@S0 (over dead wvt/xb)
    // 7. T(Wo) -> wot@S1 head (Q dead)
    // 8. gemm256<1>(AO@S0, wot@S1h) -> d_out fp32 (D0+D1; Vt,K dead)
    const size_t HALF = (size_t)M_TOT * DM * 2;  // 16 MB
    char* S0 = (char*)d_ws;
    char* S1 = (char*)d_ws + HALF;
    char* D0 = (char*)d_out;
    char* D1 = (char*)d_out + HALF;

    u16* xb  = (u16*)S0;
    u16* Qb  = (u16*)S1;
    u16* Kb  = (u16*)D1;
    u16* Vt  = (u16*)D0;
    u16* AOb = (u16*)S0;
    u16* wqk = (u16*)D0;   // 4 MB
    u16* wvt = (u16*)S0;   // 2 MB over dead xb
    u16* wot = (u16*)S1;   // 2 MB over dead Q

    const float cscale = 0.125f * 1.44269504088896f;  // 1/sqrt(64) * log2(e)
    dim3 tg2(32, 32, 2);
    dim3 tg1(32, 32, 1);

    // 1) x -> bf16
    int n4 = M_TOT * DM / 4;
    cvt_bf16_kernel<<<n4 / 256, 256, 0, stream>>>(x, xb, n4);

    // 2-3) fused Q,K projection (Q pre-scaled), 256x128 tiles
    transpose_w_kernel<<<tg2, 256, 0, stream>>>(Wq, Wk, wqk);
    dim3 gqk(M_TOT / 256, 2048 / 128);   // 32 x 16 = 512 blocks
    gemm256<0><<<gqk, 512, 0, stream>>>(xb, wqk, (void*)Qb, (void*)Kb, cscale);

    // 4-5) V projection with fused transpose (fp32 A from d_in)
    transpose_w_kernel<<<tg1, 256, 0, stream>>>(Wv, Wv, wvt);
    dim3 gv(M_TOT / 128, DM / 128);      // 64 x 8
    gemm_v<<<gv, 256, 0, stream>>>(x, wvt, Vt);

    // 6) attention
    dim3 ag(BH, 16);
    attn_kernel<<<ag, 256, 0, stream>>>(Qb, Kb, Vt, AOb);

    // 7-8) output projection straight into d_out, 256x128 tiles
    transpose_w_kernel<<<tg1, 256, 0, stream>>>(Wo, Wo, wot);
    dim3 go(M_TOT / 256, DM / 128);      // 32 x 8 = 256 blocks
    gemm256<1><<<go, 512, 0, stream>>>(AOb, wot, (void*)out, (void*)out, 1.0f);
}